// Round 4
// baseline (403.348 us; speedup 1.0000x reference)
//
#include <hip/hip_runtime.h>
#include <hip/hip_bf16.h>

typedef __hip_bfloat16 bf16;
typedef __attribute__((ext_vector_type(8))) short short8;
typedef __attribute__((ext_vector_type(16))) float f32x16;

__device__ __forceinline__ float b2f(bf16 x) { return __bfloat162float(x); }
__device__ __forceinline__ bf16  f2b(float x) { return __float2bfloat16(x); }
__device__ __forceinline__ short f2bs(float x) {
    bf16 h = __float2bfloat16(x);
    return *reinterpret_cast<short*>(&h);
}
__device__ __forceinline__ float s2f(short s) {
    bf16 h; *reinterpret_cast<short*>(&h) = s; return __bfloat162float(h);
}
// async global->LDS, 16B per lane; dst must be wave-uniform (HW adds lane*16)
__device__ __forceinline__ void gload_lds16(const void* g, void* l) {
    __builtin_amdgcn_global_load_lds(
        (const __attribute__((address_space(1))) void*)g,
        (__attribute__((address_space(3))) void*)l, 16, 0, 0);
}

constexpr int N_ = 8, C_ = 64, T_ = 256, VQ_ = 90, VK_ = 50, S_ = 4, L_ = 4;
constexpr int Tq_ = T_ - L_;     // 252
constexpr int NL  = L_ + 1;      // 5 lags
constexpr int COLS = T_ * VQ_;   // 23040
constexpr float EPSf = 1e-5f;
constexpr int NSL = 16;          // score partial K-slices

// Shared-memory pool for the M=256/K=64 GEMM template (k1, k5)
union SMemG {
    struct { short A[8 * 256 * 8]; short B[8 * 128 * 8]; } ab; // 32KB + 16KB
    short buf[4][64 * 66];                                     // 33.8KB epilogue
};

// ---------------------------------------------------------------- K0: fold Wq into key side
__global__ __launch_bounds__(64)
void k0_precompute(const float* __restrict__ Wq, const float* __restrict__ bq,
                   const float* __restrict__ Wk, const float* __restrict__ bk,
                   short* __restrict__ MtA, float* __restrict__ bMp,
                   float* __restrict__ wb, float* __restrict__ cb) {
    int s  = blockIdx.x >> 6;
    int ci = blockIdx.x & 63;
    int cj = threadIdx.x;
    float m = 0.f;
    for (int c = 0; c < C_; ++c)
        m += Wq[(s * C_ + c) * C_ + ci] * Wk[(s * C_ + c) * C_ + cj];
    MtA[((cj >> 3) * 256 + s * C_ + ci) * 8 + (cj & 7)] = f2bs(m);
    if (cj == 0) {
        float v = 0.f;
        for (int c = 0; c < C_; ++c)
            v += Wq[(s * C_ + c) * C_ + ci] * bk[s * C_ + c];
        bMp[s * C_ + ci] = v;
    }
    if (ci == 0) {
        float v = 0.f;
        for (int c = 0; c < C_; ++c)
            v += bq[s * C_ + c] * Wk[(s * C_ + c) * C_ + cj];
        wb[s * C_ + cj] = v;
        if (cj == 0) {
            float v2 = 0.f;
            for (int c = 0; c < C_; ++c)
                v2 += bq[s * C_ + c] * bk[s * C_ + c];
            cb[s] = v2;
        }
    }
}

// ---------------------------------------------------------------- K0b: fold Wout into Wv
__global__ __launch_bounds__(256)
void k0b_wos(const float* __restrict__ Wout, const float* __restrict__ bout,
             const float* __restrict__ Wv, const float* __restrict__ bv,
             short* __restrict__ WosA, float* __restrict__ bos) {
    int cj = blockIdx.x;
    __shared__ float wvcol[C_];
    if (threadIdx.x < C_) wvcol[threadIdx.x] = Wv[threadIdx.x * C_ + cj];
    __syncthreads();
    int p = threadIdx.x;       // p = s*64 + o
    int s = p >> 6, o = p & 63;
    float acc = 0.f;
    for (int c = 0; c < C_; ++c)
        acc += Wout[o * (S_ * C_) + s * C_ + c] * wvcol[c];
    WosA[((cj >> 3) * 256 + p) * 8 + (cj & 7)] = f2bs(acc);
    if (cj == 0 && p < C_) {
        float a = bout[p];
        for (int k = 0; k < S_ * C_; ++k)
            a += Wout[p * (S_ * C_) + k] * bv[k & 63];
        bos[p] = a;
    }
}

// ---------------------------------------------------------------- K0c: xqT[n][g][t][u96][cc8] bf16
__global__ __launch_bounds__(256)
void k0c_xqt(const float* __restrict__ xq, short* __restrict__ xqT) {
    int tt = blockIdx.x;            // 64 tiles of 4 t
    int g  = blockIdx.y;
    int n  = blockIdx.z;
    int t0 = tt * 4;
    __shared__ float lds[8 * 360];  // [c][t*90+u], 11.5KB
    int tid = threadIdx.x;
    const float* src = xq + ((size_t)(n * 64 + g * 8) * 256 + t0) * 90;
#pragma unroll
    for (int i = tid; i < 720; i += 256) {
        int c = i / 90, r = i % 90;
        float4 v = *(const float4*)(src + (size_t)c * 23040 + r * 4);
        *(float4*)(&lds[c * 360 + r * 4]) = v;
    }
    __syncthreads();
    for (int e = tid; e < 4 * 96; e += 256) {
        int t = e / 96, u = e % 96;
        short8 pk;
#pragma unroll
        for (int j = 0; j < 8; ++j)
            pk[j] = (u < 90) ? f2bs(lds[j * 360 + t * 90 + u]) : (short)0;
        *(short8*)(xqT + (((size_t)(n * 8 + g) * 256 + t0 + t) * 96 + u) * 8) = pk;
    }
}

// ---------------------------------------------------------------- K1: MFMA kq = Mt @ x_k + bM -> kqT
__global__ __launch_bounds__(256)
void k1_mfma(const float* __restrict__ x_k, const short* __restrict__ MtA,
             const float* __restrict__ bMp, short* __restrict__ kqT) {
    int tb = blockIdx.x, n = blockIdx.y;
    int t0 = tb * 2;
    __shared__ SMemG u;
    __shared__ float bmp_s[256];
    __shared__ float xs[3200];       // 12.8KB: [c32][100] = 32 ch x (2t x 50v)
    int tid = threadIdx.x;
    if (tid < 256) bmp_s[tid] = bMp[tid];
    for (int i = tid; i < 2048; i += 256)
        ((short8*)u.ab.A)[i] = ((const short8*)MtA)[i];
#pragma unroll
    for (int p = 0; p < 2; ++p) {
        for (int i4 = tid; i4 < 800; i4 += 256) {
            int c32 = i4 / 25, o = i4 % 25;
            *(float4*)(&xs[c32 * 100 + o * 4]) =
                *(const float4*)(x_k + ((size_t)(n * 64 + p * 32 + c32) * 256 + t0) * 50 + o * 4);
        }
        __syncthreads();
        for (int m = tid; m < 512; m += 256) {
            int kgl = m >> 7, c = m & 127, t = c >> 6, v = c & 63;
            short8 pk;
            if (v < VK_) {
#pragma unroll
                for (int j = 0; j < 8; ++j) pk[j] = f2bs(xs[(kgl * 8 + j) * 100 + t * 50 + v]);
            } else {
#pragma unroll
                for (int j = 0; j < 8; ++j) pk[j] = 0;
            }
            *(short8*)(u.ab.B + ((p * 4 + kgl) * 128 + c) * 8) = pk;
        }
        __syncthreads();
    }
    int wave = tid >> 6, lane = tid & 63, q = lane >> 5, c32 = lane & 31;
    f32x16 acc[2][4];
#pragma unroll
    for (int mt = 0; mt < 2; ++mt) {
#pragma unroll
        for (int r = 0; r < 16; ++r) {
            float b = bmp_s[wave * 64 + mt * 32 + (r & 3) + 8 * (r >> 2) + 4 * q];
#pragma unroll
            for (int nt = 0; nt < 4; ++nt) acc[mt][nt][r] = b;
        }
    }
#pragma unroll
    for (int ks = 0; ks < 4; ++ks) {
        int kg = 2 * ks + q;
        short8 a0 = *(const short8*)(u.ab.A + (kg * 256 + wave * 64 + c32) * 8);
        short8 a1 = *(const short8*)(u.ab.A + (kg * 256 + wave * 64 + 32 + c32) * 8);
#pragma unroll
        for (int nt = 0; nt < 4; ++nt) {
            short8 b = *(const short8*)(u.ab.B + (kg * 128 + nt * 32 + c32) * 8);
            acc[0][nt] = __builtin_amdgcn_mfma_f32_32x32x16_bf16(a0, b, acc[0][nt], 0, 0, 0);
            acc[1][nt] = __builtin_amdgcn_mfma_f32_32x32x16_bf16(a1, b, acc[1][nt], 0, 0, 0);
        }
    }
    __syncthreads();  // A/B dead, buf becomes live
    int ns = n * 4 + wave;
    for (int t = 0; t < 2; ++t) {
#pragma unroll
        for (int mt = 0; mt < 2; ++mt)
#pragma unroll
            for (int ntl = 0; ntl < 2; ++ntl) {
                f32x16 A = acc[mt][t * 2 + ntl];
                int cloc = ntl * 32 + c32;
#pragma unroll
                for (int r = 0; r < 16; ++r) {
                    int ci = mt * 32 + (r & 3) + 8 * (r >> 2) + 4 * q;
                    u.buf[wave][cloc * 66 + ci] = f2bs(A[r]);
                }
            }
        __syncthreads();
        if (lane < VK_) {
#pragma unroll
            for (int g = 0; g < 8; ++g) {
                short8 pk;
#pragma unroll
                for (int j = 0; j < 8; ++j) pk[j] = u.buf[wave][lane * 66 + g * 8 + j];
                *(short8*)(kqT + ((((size_t)ns * 8 + g) * 256 + t0 + t) * VK_ + lane) * 8) = pk;
            }
        }
        __syncthreads();
    }
}

// ---------------------------------------------------------------- K3b: kbsum from x_k sliding sums
__global__ __launch_bounds__(128)
void k3b_kbsum(const float* __restrict__ x_k, const float* __restrict__ wb,
               const float* __restrict__ cb, float* __restrict__ kbsum) {
    int cjg = blockIdx.x;  // 32 groups of 2 cj
    int n = blockIdx.y;
    __shared__ float S[2][NL][VK_];
    for (int pr = threadIdx.x; pr < 2 * VK_; pr += 128) {
        int cjl = pr / VK_, v = pr % VK_;
        const float* base = x_k + ((size_t)(n * 64 + cjg * 2 + cjl) * 256) * VK_ + v;
        float a = 0.f;
        for (int t = 0; t < Tq_; ++t) a += base[t * VK_];
        S[cjl][0][v] = a;
        float run = a;
        for (int l = 1; l < NL; ++l) {
            run += base[(251 + l) * VK_] - base[(l - 1) * VK_];
            S[cjl][l][v] = run;
        }
    }
    __syncthreads();
    for (int e = threadIdx.x; e < S_ * NL * VK_; e += 128) {
        int s = e / (NL * VK_), r = e % (NL * VK_), l = r / VK_, v = r % VK_;
        float a = wb[s * 64 + cjg * 2] * S[0][l][v] + wb[s * 64 + cjg * 2 + 1] * S[1][l][v];
        if (cjg == 0) a += (float)Tq_ * cb[s];
        atomicAdd(&kbsum[((size_t)(n * 4 + s) * NL + l) * VK_ + v], a);
    }
}

// ---------------------------------------------------------------- K3: MFMA scores
// v4: v2 structure (12-t chunks, depth-1 counted vmcnt, 62KB dbuf) + XCD-aware
// block swizzle (all 8 blocks sharing an A-slice -> same XCD L2) + setprio.
__global__ __launch_bounds__(256)
void k3_mfma(const short* __restrict__ xqT, const short* __restrict__ kqT,
             float* __restrict__ partial) {
    // XCD swizzle: linear id round-robins across 8 XCDs; make slice = (n,g)
    // a function of (lin & 7) so all its blocks land on one XCD.
    int lin = blockIdx.x + 16 * blockIdx.y;   // 0..511
    int grp = lin & 7;                        // XCD
    int idx = lin >> 3;                       // 0..63
    int slice = grp + 8 * (idx >> 3);         // n*8+g, 8 slices per XCD
    int sub = idx & 7;                        // s*2+half
    int n = slice >> 3, g = slice & 7;
    int s = sub >> 1, half = sub & 1;
    int ns = n * 4 + s;
    int gx = g * 2 + half;                    // partial slice index 0..15
    __shared__ __align__(16) short sbuf[2][15872];   // 2 x 31744B = 62KB
    int tid = threadIdx.x;
    int wave = tid >> 6, lane = tid & 63;
    int q = lane >> 5, nl = lane & 31;
    int n1 = wave * 64 + nl, n2 = n1 + 32;
    int nc1 = min(n1, 249), nc2 = min(n2, 249);
    int l1 = nc1 / VK_, v1 = nc1 % VK_;
    int l2 = nc2 / VK_, v2 = nc2 % VK_;
    int bo1 = ((q + l1) * VK_ + v1) * 8;
    int bo2 = ((q + l2) * VK_ + v2) * 8;
    int ao = (q * 96 + nl) * 8;
    f32x16 acc[6];
#pragma unroll
    for (int i = 0; i < 6; ++i)
#pragma unroll
        for (int r = 0; r < 16; ++r) acc[i][r] = 0.f;
    const short* asrc = xqT + (size_t)(n * 8 + g) * 256 * 768;
    const short* bsrc = kqT + (size_t)(ns * 8 + g) * 256 * 400;
    int c0 = half * 10, nch = half ? 11 : 10;
    int ncall = (wave == 3) ? 7 : 8;

    auto stage = [&](int buf, int ch) {
        int t0 = ch * 12;
        const short8* aS = (const short8*)(asrc + t0 * 768);
        const short8* bS = (const short8*)(bsrc + t0 * 400);
        char* db = (char*)(&sbuf[buf][0]);
        for (int it = 0; it < ncall; ++it) {
            int call = wave * 8 + it;            // 0..30 (call 31 never issued)
            int i = call * 64 + lane;            // linear lane-load index
            const void* gsrc = (i < 1152) ? (const void*)(aS + i)
                                          : (const void*)(bS + min(i - 1152, 799));
            gload_lds16(gsrc, db + call * 1024); // dst wave-uniform; HW adds lane*16
        }
    };

    stage(0, c0);
    for (int ci = 0; ci < nch; ++ci) {
        int cur = ci & 1;
        if (ci + 1 < nch) {
            stage(cur ^ 1, c0 + ci + 1);
            // wait only for the current chunk's loads; keep the prefetch in flight
            if (wave == 3) asm volatile("s_waitcnt vmcnt(7)" ::: "memory");
            else           asm volatile("s_waitcnt vmcnt(8)" ::: "memory");
        } else {
            asm volatile("s_waitcnt vmcnt(0)" ::: "memory");
        }
        __builtin_amdgcn_s_barrier();
        const short* xa  = &sbuf[cur][0];
        const short* kbs = &sbuf[cur][9216];     // B starts at byte 18432
        __builtin_amdgcn_s_setprio(1);
#pragma unroll
        for (int ts = 0; ts < 6; ++ts) {
            short8 a0 = *(const short8*)(xa + ao + ts * 1536);
            short8 a1 = *(const short8*)(xa + ao + 256 + ts * 1536);
            short8 a2 = *(const short8*)(xa + ao + 512 + ts * 1536);
            short8 b0 = *(const short8*)(kbs + bo1 + ts * 800);
            short8 b1 = *(const short8*)(kbs + bo2 + ts * 800);
            acc[0] = __builtin_amdgcn_mfma_f32_32x32x16_bf16(a0, b0, acc[0], 0, 0, 0);
            acc[1] = __builtin_amdgcn_mfma_f32_32x32x16_bf16(a1, b0, acc[1], 0, 0, 0);
            acc[2] = __builtin_amdgcn_mfma_f32_32x32x16_bf16(a2, b0, acc[2], 0, 0, 0);
            acc[3] = __builtin_amdgcn_mfma_f32_32x32x16_bf16(a0, b1, acc[3], 0, 0, 0);
            acc[4] = __builtin_amdgcn_mfma_f32_32x32x16_bf16(a1, b1, acc[4], 0, 0, 0);
            acc[5] = __builtin_amdgcn_mfma_f32_32x32x16_bf16(a2, b1, acc[5], 0, 0, 0);
        }
        __builtin_amdgcn_s_setprio(0);
        __builtin_amdgcn_s_barrier();            // protect buf[cur] before re-stage
    }
#pragma unroll
    for (int inb = 0; inb < 2; ++inb) {
        int ng = wave * 64 + inb * 32 + nl;
        if (ng < 250) {
            int l = ng / VK_, v = ng % VK_;
            float* pb = partial + ((((size_t)ns * 5 + l) * 90) * NSL + gx) * VK_ + v;
#pragma unroll
            for (int iu = 0; iu < 3; ++iu) {
#pragma unroll
                for (int r = 0; r < 16; ++r) {
                    int u2 = iu * 32 + (r & 3) + 8 * (r >> 2) + 4 * q;
                    if (u2 < 90) pb[(size_t)u2 * NSL * VK_] = acc[inb * 3 + iu][r];
                }
            }
        }
    }
}

// ---------------------------------------------------------------- K4: reduce slices + combine lags + softmax
__global__ __launch_bounds__(256)
void k4_softmax(const float* __restrict__ partial, const float* __restrict__ kbsum,
                bf16* __restrict__ att) {
    int ug = blockIdx.x;
    int ns = blockIdx.y;
    int u0 = ug * 15;
    __shared__ float sred[NL * 15 * VK_];
    for (int idx = threadIdx.x; idx < NL * 15 * VK_; idx += 256) {
        int l = idx / (15 * VK_), r = idx % (15 * VK_);
        int u2 = r / VK_, v = r % VK_;
        const float* p = partial + (((size_t)(ns * NL + l) * 90 + u0 + u2) * NSL) * VK_ + v;
        float a = 0.f;
#pragma unroll
        for (int sl = 0; sl < NSL; ++sl) a += p[sl * VK_];
        sred[idx] = a;
    }
    __syncthreads();
    if (threadIdx.x < 15) {
        int u2 = threadIdx.x;
        const float inv_scale = rsqrtf((float)(C_ * Tq_));
        float pv[VK_];
        float pmax = -1e30f;
#pragma unroll
        for (int v = 0; v < VK_; ++v) {
            float mx = -1e30f, mn = 0.f;
#pragma unroll
            for (int l = 0; l < NL; ++l) {
                float sl = (sred[(l * 15 + u2) * VK_ + v] + kbsum[((size_t)ns * NL + l) * VK_ + v]) * inv_scale;
                mx = fmaxf(mx, sl); mn += sl;
            }
            pv[v] = 0.5f * (mx + mn * (1.f / NL));
            pmax = fmaxf(pmax, pv[v]);
        }
        float sum = 0.f;
#pragma unroll
        for (int v = 0; v < VK_; ++v) { pv[v] = __expf(pv[v] - pmax); sum += pv[v]; }
        float inv = 1.f / sum;
#pragma unroll
        for (int v = 0; v < VK_; ++v)
            att[((size_t)ns * VQ_ + u0 + u2) * VK_ + v] = f2b(pv[v] * inv);
    }
}

// ---------------------------------------------------------------- K5: MFMA wv_pack
__global__ __launch_bounds__(256)
void k5_mfma(const float* __restrict__ x_v, const short* __restrict__ WosA,
             short* __restrict__ wv_pack) {
    int tb = blockIdx.x, n = blockIdx.y;
    int t0 = tb * 2;
    __shared__ SMemG u;
    __shared__ float xs[3200];       // 12.8KB
    int tid = threadIdx.x;
    for (int i = tid; i < 2048; i += 256)
        ((short8*)u.ab.A)[i] = ((const short8*)WosA)[i];
#pragma unroll
    for (int p = 0; p < 2; ++p) {
        for (int i4 = tid; i4 < 800; i4 += 256) {
            int c32 = i4 / 25, o = i4 % 25;
            *(float4*)(&xs[c32 * 100 + o * 4]) =
                *(const float4*)(x_v + ((size_t)(n * 64 + p * 32 + c32) * 256 + t0) * 50 + o * 4);
        }
        __syncthreads();
        for (int m = tid; m < 512; m += 256) {
            int kgl = m >> 7, c = m & 127, t = c >> 6, v = c & 63;
            short8 pk;
            if (v < VK_) {
#pragma unroll
                for (int j = 0; j < 8; ++j) pk[j] = f2bs(xs[(kgl * 8 + j) * 100 + t * 50 + v]);
            } else {
#pragma unroll
                for (int j = 0; j < 8; ++j) pk[j] = 0;
            }
            *(short8*)(u.ab.B + ((p * 4 + kgl) * 128 + c) * 8) = pk;
        }
        __syncthreads();
    }
    int wave = tid >> 6, lane = tid & 63, q = lane >> 5, c32 = lane & 31;
    f32x16 acc[2][4];
#pragma unroll
    for (int mt = 0; mt < 2; ++mt)
#pragma unroll
        for (int nt = 0; nt < 4; ++nt)
#pragma unroll
            for (int r = 0; r < 16; ++r) acc[mt][nt][r] = 0.f;
#pragma unroll
    for (int ks = 0; ks < 4; ++ks) {
        int kg = 2 * ks + q;
        short8 a0 = *(const short8*)(u.ab.A + (kg * 256 + wave * 64 + c32) * 8);
        short8 a1 = *(const short8*)(u.ab.A + (kg * 256 + wave * 64 + 32 + c32) * 8);
#pragma unroll
        for (int nt = 0; nt < 4; ++nt) {
            short8 b = *(const short8*)(u.ab.B + (kg * 128 + nt * 32 + c32) * 8);
            acc[0][nt] = __builtin_amdgcn_mfma_f32_32x32x16_bf16(a0, b, acc[0][nt], 0, 0, 0);
            acc[1][nt] = __builtin_amdgcn_mfma_f32_32x32x16_bf16(a1, b, acc[1][nt], 0, 0, 0);
        }
    }
    __syncthreads();
    for (int t = 0; t < 2; ++t) {
#pragma unroll
        for (int mt = 0; mt < 2; ++mt)
#pragma unroll
            for (int ntl = 0; ntl < 2; ++ntl) {
                f32x16 A = acc[mt][t * 2 + ntl];
                int cloc = ntl * 32 + c32;
#pragma unroll
                for (int r = 0; r < 16; ++r) {
                    int o = mt * 32 + (r & 3) + 8 * (r >> 2) + 4 * q;
                    u.buf[wave][cloc * 66 + o] = f2bs(A[r]);
                }
            }
        __syncthreads();
        short* dst = wv_pack + (((size_t)(n * 256 + t0 + t)) * 32 + wave * 8) * 512;
#pragma unroll
        for (int vg = 0; vg < 8; ++vg) {
            short8 pk;
#pragma unroll
            for (int j = 0; j < 8; ++j) pk[j] = u.buf[wave][(vg * 8 + j) * 66 + lane];
            *(short8*)(dst + (size_t)vg * 512 + lane * 8) = pk;
        }
        __syncthreads();
    }
}

// ---------------------------------------------------------------- K6: MFMA y-path, K=256
__global__ __launch_bounds__(256)
void k6_mfma(const bf16* __restrict__ att, const short* __restrict__ wv_pack,
             const float* __restrict__ bos, bf16* __restrict__ out_pre) {
    int tc = blockIdx.x, n = blockIdx.y;
    __shared__ __align__(16) short att_p[32 * 96 * 8]; // 48KB [g][u][j8]
    __shared__ float bos_s[64];
    int tid = threadIdx.x;
    if (tid < 64) bos_s[tid] = bos[tid];
    for (int m = tid; m < 96 * 256; m += 256) {
        int u2 = m >> 8, k = m & 255;
        int s = k >> 6, vs = k & 63;
        short val = 0;
        if (u2 < 90 && vs < VK_) {
            bf16 h = att[((size_t)(n * 4 + s) * 90 + u2) * VK_ + vs];
            val = *reinterpret_cast<short*>(&h);
        }
        att_p[((k >> 3) * 96 + u2) * 8 + (k & 7)] = val;
    }
    __syncthreads();
    int wave = tid >> 6, lane = tid & 63;
    int q = lane >> 5, c = lane & 31;
    int t = tc * 4 + wave;
    f32x16 acc[6];
#pragma unroll
    for (int ot = 0; ot < 2; ++ot)
#pragma unroll
        for (int r = 0; r < 16; ++r) {
            float b = bos_s[ot * 32 + (r & 3) + 8 * (r >> 2) + 4 * q];
            acc[ot * 3 + 0][r] = b; acc[ot * 3 + 1][r] = b; acc[ot * 3 + 2][r] = b;
        }
    const short* wbase = wv_pack + (size_t)(n * 256 + t) * (32 * 512);
#pragma unroll
    for (int st = 0; st < 16; ++st) {
        int gq = 2 * st + q;
        short8 a0 = *(const short8*)(wbase + (gq * 64 + c) * 8);
        short8 a1 = *(const short8*)(wbase + (gq * 64 + 32 + c) * 8);
        short8 b0 = *(const short8*)(att_p + (gq * 96 + c) * 8);
        short8 b1 = *(const short8*)(att_p + (gq * 96 + 32 + c) * 8);
        short8 b2 = *(const short8*)(att_p + (gq * 96 + 64 + c) * 8);
        acc[0] = __builtin_amdgcn_mfma_f32_32x32x16_bf16(a0, b0, acc[0], 0, 0, 0);
        acc[1] = __builtin_amdgcn_mfma_f32_32x32x16_bf16(a0, b1, acc[1], 0, 0, 0);
        acc[2] = __builtin_amdgcn_mfma_f32_32x32x16_bf16(a0, b2, acc[2], 0, 0, 0);
        acc[3] = __builtin_amdgcn_mfma_f32_32x32x16_bf16(a1, b0, acc[3], 0, 0, 0);
        acc[4] = __builtin_amdgcn_mfma_f32_32x32x16_bf16(a1, b1, acc[4], 0, 0, 0);
        acc[5] = __builtin_amdgcn_mfma_f32_32x32x16_bf16(a1, b2, acc[5], 0, 0, 0);
    }
#pragma unroll
    for (int ot = 0; ot < 2; ++ot)
#pragma unroll
        for (int ut = 0; ut < 3; ++ut) {
            int u2 = ut * 32 + c;
            if (u2 < 90) {
                f32x16 A = acc[ot * 3 + ut];
#pragma unroll
                for (int r = 0; r < 16; ++r) {
                    int o = ot * 32 + (r & 3) + 8 * (r >> 2) + 4 * q;
                    out_pre[((size_t)(n * 64 + o) * 256 + t) * 90 + u2] = f2b(A[r]);
                }
            }
        }
}

// ---------------------------------------------------------------- K7: MFMA down conv
__global__ __launch_bounds__(256)
void k7_mfma(const float* __restrict__ X, const float* __restrict__ W,
             const float* __restrict__ bias, bf16* __restrict__ out) {
    int cb = blockIdx.x, n = blockIdx.y;
    int col0 = cb * 256;
    __shared__ __align__(16) short A[8 * 64 * 8];  // 8KB
    __shared__ __align__(16) short B[8 * 256 * 8]; // 32KB
    __shared__ float bias_s[64];
    __shared__ float xs[2048];                     // 8KB: [cl][256]
    int tid = threadIdx.x;
    if (tid < 64) bias_s[tid] = bias[tid];
    for (int idx = tid; idx < 4096; idx += 256) {
        int o = idx >> 6, k = idx & 63;
        A[((k >> 3) * 64 + o) * 8 + (k & 7)] = f2bs(W[o * 64 + k]);
    }
#pragma unroll
    for (int p = 0; p < 8; ++p) {
        for (int i4 = tid; i4 < 512; i4 += 256) {
            int cl = i4 >> 6, o = i4 & 63;
            *(float4*)(&xs[cl * 256 + o * 4]) =
                *(const float4*)(X + (size_t)(n * 64 + p * 8 + cl) * COLS + col0 + o * 4);
        }
        __syncthreads();
        {
            short8 pk;
#pragma unroll
            for (int j = 0; j < 8; ++j) pk[j] = f2bs(xs[j * 256 + tid]);
            *(short8*)(B + (p * 256 + tid) * 8) = pk;
        }
        __syncthreads();
    }
    int wave = tid >> 6, lane = tid & 63, q = lane >> 5, c32 = lane & 31;
    f32x16 acc[2][2];
#pragma unroll
    for (int mt = 0; mt < 2; ++mt)
#pragma unroll
        for (int r = 0; r < 16; ++r) {
            float b = bias_s[mt * 32 + (r & 3) + 8 * (r >> 2) + 4 * q];
            acc[mt][0][r] = b; acc[mt][1][r] = b;
        }
#pragma unroll
    for (int ks = 0; ks < 4; ++ks) {
        int kg = 2 * ks + q;
        short8 a0 = *(const short8*)(A + (kg * 64 + c32) * 8);
        short8 a1 = *(const short8*)(A + (kg * 64 + 32 + c32) * 8);
#pragma unroll
        for (int i = 0; i < 2; ++i) {
            short8 b = *(const short8*)(B + (kg * 256 + (wave * 2 + i) * 32 + c32) * 8);
            acc[0][i] = __builtin_amdgcn_mfma_f32_32x32x16_bf16(a0, b, acc[0][i], 0, 0, 0);
            acc[1][i] = __builtin_amdgcn_mfma_f32_32x32x16_bf16(a1, b, acc[1][i], 0, 0, 0);
        }
    }
#pragma unroll
    for (int mt = 0; mt < 2; ++mt)
#pragma unroll
        for (int i = 0; i < 2; ++i) {
            int col = col0 + (wave * 2 + i) * 32 + c32;
#pragma unroll
            for (int r = 0; r < 16; ++r) {
                int o = mt * 32 + (r & 3) + 8 * (r >> 2) + 4 * q;
                out[(size_t)(n * 64 + o) * COLS + col] = f2b(acc[mt][i][r]);
            }
        }
}

// ---------------------------------------------------------------- K8: per-channel sum/sumsq (vectorized short8)
__global__ __launch_bounds__(256)
void k8_stats(const bf16* __restrict__ out_pre, const bf16* __restrict__ d_pre,
              float* __restrict__ stats) {
    int path = blockIdx.x >> 9;
    int b = blockIdx.x & 511;
    int o = b >> 3, n = b & 7;
    const bf16* p = (path ? d_pre : out_pre) + ((size_t)n * C_ + o) * COLS;
    float s = 0.f, sq = 0.f;
    for (int i8 = threadIdx.x; i8 < COLS / 8; i8 += 256) {
        short8 v8 = *(const short8*)(p + i8 * 8);
#pragma unroll
        for (int j = 0; j < 8; ++j) {
            float x = s2f(v8[j]);
            s += x; sq += x * x;
        }
    }
#pragma unroll
    for (int off = 32; off > 0; off >>= 1) {
        s  += __shfl_down(s, off, 64);
        sq += __shfl_down(sq, off, 64);
    }
    __shared__ float red[8];
    int wid = threadIdx.x >> 6, lane = threadIdx.x & 63;
    if (lane == 0) { red[wid * 2] = s; red[wid * 2 + 1] = sq; }
    __syncthreads();
    if (threadIdx.x == 0) {
        float S = 0.f, Q = 0.f;
        for (int w2 = 0; w2 < 4; ++w2) { S += red[w2 * 2]; Q += red[w2 * 2 + 1]; }
        atomicAdd(&stats[path * 128 + o * 2], S);
        atomicAdd(&stats[path * 128 + o * 2 + 1], Q);
    }
}

// ---------------------------------------------------------------- K9: BN + BN + add + leaky relu (vectorized)
__global__ __launch_bounds__(256)
void k9_final(const bf16* __restrict__ out_pre, const bf16* __restrict__ d_pre,
              const float* __restrict__ stats,
              const float* __restrict__ gamma_out, const float* __restrict__ beta_out,
              const float* __restrict__ gamma_down, const float* __restrict__ beta_down,
              float* __restrict__ out) {
    const float invM = 1.f / ((float)N_ * COLS);
    size_t total8 = (size_t)N_ * C_ * COLS / 8;   // 1474560
    size_t stride = (size_t)gridDim.x * blockDim.x;
    for (size_t i8 = (size_t)blockIdx.x * blockDim.x + threadIdx.x; i8 < total8; i8 += stride) {
        size_t idx = i8 * 8;
        int o = (int)((idx / COLS) % C_);         // COLS % 8 == 0 -> o uniform over pack
        float my = stats[o * 2] * invM;
        float vy = stats[o * 2 + 1] * invM - my * my;
        float md = stats[128 + o * 2] * invM;
        float vd = stats[128 + o * 2 + 1] * invM - md * md;
        float ay = rsqrtf(vy + EPSf) * gamma_out[o];
        float by = beta_out[o] - my * ay;
        float ad = rsqrtf(vd + EPSf) * gamma_down[o];
        float bd = beta_down[o] - md * ad;
        short8 y8 = *(const short8*)(out_pre + idx);
        short8 d8 = *(const short8*)(d_pre + idx);
        float rr[8];
#pragma unroll
        for (int j = 0; j < 8; ++j) {
            float r = (s2f(y8[j]) * ay + by) + (s2f(d8[j]) * ad + bd);
            rr[j] = r > 0.f ? r : 0.1f * r;
        }
        *(float4*)(out + idx)     = make_float4(rr[0], rr[1], rr[2], rr[3]);
        *(float4*)(out + idx + 4) = make_float4(rr[4], rr[5], rr[6], rr[7]);
    }
}

// ----------------------------------------------------------------
extern "C" void kernel_launch(void* const* d_in, const int* in_sizes, int n_in,
                              void* d_out, int out_size, void* d_ws, size_t ws_size,
                              hipStream_t stream) {
    (void)in_sizes; (void)n_in; (void)out_size; (void)ws_size;
    const float* x_q  = (const float*)d_in[0];
    const float* x_k  = (const float*)d_in[1];
    const float* x_v  = (const float*)d_in[2];
    const float* Wq   = (const float*)d_in[3];
    const float* bq   = (const float*)d_in[4];
    const float* Wk   = (const float*)d_in[5];
    const float* bk   = (const float*)d_in[6];
    const float* Wv   = (const float*)d_in[7];
    const float* bv   = (const float*)d_in[8];
    const float* Wout = (const float*)d_in[9];
    const float* bout = (const float*)d_in[10];
    const float* gamma_out  = (const float*)d_in[11];
    const float* beta_out   = (const float*)d_in[12];
    const float* Wdown = (const float*)d_in[13];
    const float* bdown = (const float*)d_in[14];
    const float* gamma_down = (const float*)d_in[15];
    const float* beta_down  = (const float*)d_in[16];

    char* w = (char*)d_ws;
    size_t off = 0;
    auto nxt = [&](size_t bytes) {
        char* p = w + off;
        off += (bytes + 255) & ~(size_t)255;
        return p;
    };
    // small persistent buffers
    short* MtA   = (short*)nxt((size_t)8 * 256 * 8 * 2);   // 32KB
    float* bMp   = (float*)nxt(256 * 4);
    float* wbp   = (float*)nxt((size_t)S_ * C_ * 4);
    float* cbp   = (float*)nxt((size_t)S_ * 4);
    short* WosA  = (short*)nxt((size_t)8 * 256 * 8 * 2);   // 32KB
    float* bos   = (float*)nxt((size_t)C_ * 4);
    float* kbsum = (float*)nxt((size_t)N_ * S_ * NL * VK_ * 4); // 32KB
    bf16*  att   = (bf16*)nxt((size_t)N_ * S_ * VQ_ * VK_ * 2);
    float* stats = (float*)nxt(256 * 4);
    // regionA: xqT (k0c->k3) then out_pre (k6->k8,k9)
    char* regionA = nxt((size_t)N_ * 8 * T_ * 96 * 8 * 2);            // 25.2MB
    short* xqT    = (short*)regionA;
    bf16*  out_pre = (bf16*)regionA;
    // regionB: kqT (k1->k3) then d_pre (k7->k8,k9)
    char* regionB = nxt((size_t)N_ * S_ * 8 * T_ * VK_ * 8 * 2);      // 52.4MB
    short* kqT   = (short*)regionB;
    bf16*  d_pre = (bf16*)regionB;
    // regionC: partial (k3->k4) then wv_pack (k5->k6)
    char* regionC = nxt((size_t)N_ * T_ * 32 * 512 * 2);              // 67.1MB
    float* partial = (float*)regionC;
    short* wv_pack = (short*)regionC;

    hipMemsetAsync(stats, 0, 256 * 4, stream);
    hipMemsetAsync(kbsum, 0, (size_t)N_ * S_ * NL * VK_ * 4, stream);

    k0_precompute<<<S_ * C_, 64, 0, stream>>>(Wq, bq, Wk, bk, MtA, bMp, wbp, cbp);
    k0b_wos<<<C_, 256, 0, stream>>>(Wout, bout, Wv, bv, WosA, bos);
    k0c_xqt<<<dim3(64, 8, N_), 256, 0, stream>>>(x_q, xqT);
    k1_mfma<<<dim3(128, N_), 256, 0, stream>>>(x_k, MtA, bMp, kqT);
    k3b_kbsum<<<dim3(32, N_), 128, 0, stream>>>(x_k, wbp, cbp, kbsum);
    k3_mfma<<<dim3(NSL, N_ * S_), 256, 0, stream>>>(xqT, kqT, partial);
    k4_softmax<<<dim3(6, N_ * S_), 256, 0, stream>>>(partial, kbsum, att);
    k5_mfma<<<dim3(128, N_), 256, 0, stream>>>(x_v, WosA, wv_pack);
    k6_mfma<<<dim3(T_ / 4, N_), 256, 0, stream>>>(att, wv_pack, bos, out_pre);
    k7_mfma<<<dim3(COLS / 256, N_), 256, 0, stream>>>(x_q, Wdown, bdown, d_pre);
    k8_stats<<<1024, 256, 0, stream>>>(out_pre, d_pre, stats);
    k9_final<<<2880, 256, 0, stream>>>(out_pre, d_pre, stats, gamma_out, beta_out,
                                       gamma_down, beta_down, (float*)d_out);
}

// Round 6
// 370.199 us; speedup vs baseline: 1.0895x; 1.0895x over previous
//
#include <hip/hip_runtime.h>
#include <hip/hip_bf16.h>

typedef __hip_bfloat16 bf16;
typedef __attribute__((ext_vector_type(4))) short short4v;
typedef __attribute__((ext_vector_type(8))) short short8;
typedef __attribute__((ext_vector_type(16))) float f32x16;

__device__ __forceinline__ float b2f(bf16 x) { return __bfloat162float(x); }
__device__ __forceinline__ bf16  f2b(float x) { return __float2bfloat16(x); }
__device__ __forceinline__ short f2bs(float x) {
    bf16 h = __float2bfloat16(x);
    return *reinterpret_cast<short*>(&h);
}
__device__ __forceinline__ float s2f(short s) {
    bf16 h; *reinterpret_cast<short*>(&h) = s; return __bfloat162float(h);
}
// async global->LDS, 16B per lane; dst must be wave-uniform (HW adds lane*16)
__device__ __forceinline__ void gload_lds16(const void* g, void* l) {
    __builtin_amdgcn_global_load_lds(
        (const __attribute__((address_space(1))) void*)g,
        (__attribute__((address_space(3))) void*)l, 16, 0, 0);
}

constexpr int N_ = 8, C_ = 64, T_ = 256, VQ_ = 90, VK_ = 50, S_ = 4, L_ = 4;
constexpr int Tq_ = T_ - L_;     // 252
constexpr int NL  = L_ + 1;      // 5 lags
constexpr int COLS = T_ * VQ_;   // 23040
constexpr float EPSf = 1e-5f;
constexpr int NSL = 16;          // score partial K-slices

// ---------------------------------------------------------------- K0: fold Wq into key side
__global__ __launch_bounds__(64)
void k0_precompute(const float* __restrict__ Wq, const float* __restrict__ bq,
                   const float* __restrict__ Wk, const float* __restrict__ bk,
                   short* __restrict__ MtA, float* __restrict__ bMp,
                   float* __restrict__ wb, float* __restrict__ cb) {
    int s  = blockIdx.x >> 6;
    int ci = blockIdx.x & 63;
    int cj = threadIdx.x;
    float m = 0.f;
    for (int c = 0; c < C_; ++c)
        m += Wq[(s * C_ + c) * C_ + ci] * Wk[(s * C_ + c) * C_ + cj];
    MtA[((cj >> 3) * 256 + s * C_ + ci) * 8 + (cj & 7)] = f2bs(m);
    if (cj == 0) {
        float v = 0.f;
        for (int c = 0; c < C_; ++c)
            v += Wq[(s * C_ + c) * C_ + ci] * bk[s * C_ + c];
        bMp[s * C_ + ci] = v;
    }
    if (ci == 0) {
        float v = 0.f;
        for (int c = 0; c < C_; ++c)
            v += bq[s * C_ + c] * Wk[(s * C_ + c) * C_ + cj];
        wb[s * C_ + cj] = v;
        if (cj == 0) {
            float v2 = 0.f;
            for (int c = 0; c < C_; ++c)
                v2 += bq[s * C_ + c] * bk[s * C_ + c];
            cb[s] = v2;
        }
    }
}

// ---------------------------------------------------------------- K0b: fold Wout into Wv
__global__ __launch_bounds__(256)
void k0b_wos(const float* __restrict__ Wout, const float* __restrict__ bout,
             const float* __restrict__ Wv, const float* __restrict__ bv,
             short* __restrict__ WosA, float* __restrict__ bos) {
    int cj = blockIdx.x;
    __shared__ float wvcol[C_];
    if (threadIdx.x < C_) wvcol[threadIdx.x] = Wv[threadIdx.x * C_ + cj];
    __syncthreads();
    int p = threadIdx.x;       // p = s*64 + o
    int s = p >> 6, o = p & 63;
    float acc = 0.f;
    for (int c = 0; c < C_; ++c)
        acc += Wout[o * (S_ * C_) + s * C_ + c] * wvcol[c];
    WosA[((cj >> 3) * 256 + p) * 8 + (cj & 7)] = f2bs(acc);
    if (cj == 0 && p < C_) {
        float a = bout[p];
        for (int k = 0; k < S_ * C_; ++k)
            a += Wout[p * (S_ * C_) + k] * bv[k & 63];
        bos[p] = a;
    }
}

// ---------------------------------------------------------------- K0c: xqT[n][g][t][u96][cc8] bf16
__global__ __launch_bounds__(256)
void k0c_xqt(const float* __restrict__ xq, short* __restrict__ xqT) {
    int tt = blockIdx.x;            // 64 tiles of 4 t
    int g  = blockIdx.y;
    int n  = blockIdx.z;
    int t0 = tt * 4;
    __shared__ float lds[8 * 360];  // [c][t*90+u], 11.5KB
    int tid = threadIdx.x;
    const float* src = xq + ((size_t)(n * 64 + g * 8) * 256 + t0) * 90;
#pragma unroll
    for (int i = tid; i < 720; i += 256) {
        int c = i / 90, r = i % 90;
        float4 v = *(const float4*)(src + (size_t)c * 23040 + r * 4);
        *(float4*)(&lds[c * 360 + r * 4]) = v;
    }
    __syncthreads();
    for (int e = tid; e < 4 * 96; e += 256) {
        int t = e / 96, u = e % 96;
        short8 pk;
#pragma unroll
        for (int j = 0; j < 8; ++j)
            pk[j] = (u < 90) ? f2bs(lds[j * 360 + t * 90 + u]) : (short)0;
        *(short8*)(xqT + (((size_t)(n * 8 + g) * 256 + t0 + t) * 96 + u) * 8) = pk;
    }
}

// ---------------------------------------------------------------- K1: MFMA kq = Mt @ x_k + bM -> kqT
// v3: direct dwordx2 epilogue (lane holds 4 consecutive ci), no LDS transpose.
__global__ __launch_bounds__(256)
void k1_mfma(const float* __restrict__ x_k, const short* __restrict__ MtA,
             const float* __restrict__ bMp, short* __restrict__ kqT) {
    int tb = blockIdx.x, n = blockIdx.y;
    int t0 = tb * 2;
    __shared__ __align__(16) short Ab[8 * 256 * 8]; // 32KB
    __shared__ __align__(16) short Bb[8 * 128 * 8]; // 16KB
    __shared__ float bmp_s[256];
    __shared__ float xs[3200];       // 12.8KB: [c32][100] = 32 ch x (2t x 50v)
    int tid = threadIdx.x;
    int wave = tid >> 6, lane = tid & 63, q = lane >> 5, c32 = lane & 31;
    if (tid < 256) bmp_s[tid] = bMp[tid];
    // A-stage via async global->LDS (MtA is L2-resident; 32 calls x 1KB)
    {
        const short8* Asrc = (const short8*)MtA;
#pragma unroll
        for (int it = 0; it < 8; ++it) {
            int call = wave * 8 + it;
            gload_lds16(Asrc + call * 64 + lane, (char*)Ab + call * 1024);
        }
    }
#pragma unroll
    for (int p = 0; p < 2; ++p) {
        for (int i4 = tid; i4 < 800; i4 += 256) {
            int cc = i4 / 25, o = i4 % 25;
            *(float4*)(&xs[cc * 100 + o * 4]) =
                *(const float4*)(x_k + ((size_t)(n * 64 + p * 32 + cc) * 256 + t0) * 50 + o * 4);
        }
        __syncthreads();
        for (int m = tid; m < 512; m += 256) {
            int kgl = m >> 7, c = m & 127, t = c >> 6, v = c & 63;
            short8 pk;
            if (v < VK_) {
#pragma unroll
                for (int j = 0; j < 8; ++j) pk[j] = f2bs(xs[(kgl * 8 + j) * 100 + t * 50 + v]);
            } else {
#pragma unroll
                for (int j = 0; j < 8; ++j) pk[j] = 0;
            }
            *(short8*)(Bb + ((p * 4 + kgl) * 128 + c) * 8) = pk;
        }
        __syncthreads();
    }
    asm volatile("s_waitcnt vmcnt(0)" ::: "memory");  // A-stage drained
    __builtin_amdgcn_s_barrier();
    f32x16 acc[2][4];
#pragma unroll
    for (int mt = 0; mt < 2; ++mt) {
#pragma unroll
        for (int r = 0; r < 16; ++r) {
            float b = bmp_s[wave * 64 + mt * 32 + (r & 3) + 8 * (r >> 2) + 4 * q];
#pragma unroll
            for (int nt = 0; nt < 4; ++nt) acc[mt][nt][r] = b;
        }
    }
#pragma unroll
    for (int ks = 0; ks < 4; ++ks) {
        int kg = 2 * ks + q;
        short8 a0 = *(const short8*)(Ab + (kg * 256 + wave * 64 + c32) * 8);
        short8 a1 = *(const short8*)(Ab + (kg * 256 + wave * 64 + 32 + c32) * 8);
#pragma unroll
        for (int nt = 0; nt < 4; ++nt) {
            short8 b = *(const short8*)(Bb + (kg * 128 + nt * 32 + c32) * 8);
            acc[0][nt] = __builtin_amdgcn_mfma_f32_32x32x16_bf16(a0, b, acc[0][nt], 0, 0, 0);
            acc[1][nt] = __builtin_amdgcn_mfma_f32_32x32x16_bf16(a1, b, acc[1][nt], 0, 0, 0);
        }
    }
    // direct stores: lane holds col (t,v); rows = 4-consecutive ci per rq group.
    // kqT[ns][gi=ci>>3][t][v][ci&7]; ci&7 = 4q+rr -> 8B chunk at offset 4q.
    int ns = n * 4 + wave;
#pragma unroll
    for (int mt = 0; mt < 2; ++mt)
#pragma unroll
        for (int nt = 0; nt < 4; ++nt) {
            int t = nt >> 1, v = (nt & 1) * 32 + c32;
            if (v < VK_) {
                f32x16 A = acc[mt][nt];
#pragma unroll
                for (int rq = 0; rq < 4; ++rq) {
                    short4v pk;
#pragma unroll
                    for (int rr = 0; rr < 4; ++rr) pk[rr] = f2bs(A[rq * 4 + rr]);
                    *(short4v*)(kqT + ((((size_t)(ns * 8 + mt * 4 + rq)) * 256 + t0 + t) * VK_ + v) * 8 + 4 * q) = pk;
                }
            }
        }
}

// ---------------------------------------------------------------- K3b: kbsum from x_k sliding sums
__global__ __launch_bounds__(128)
void k3b_kbsum(const float* __restrict__ x_k, const float* __restrict__ wb,
               const float* __restrict__ cb, float* __restrict__ kbsum) {
    int cjg = blockIdx.x;  // 32 groups of 2 cj
    int n = blockIdx.y;
    __shared__ float S[2][NL][VK_];
    for (int pr = threadIdx.x; pr < 2 * VK_; pr += 128) {
        int cjl = pr / VK_, v = pr % VK_;
        const float* base = x_k + ((size_t)(n * 64 + cjg * 2 + cjl) * 256) * VK_ + v;
        float a = 0.f;
        for (int t = 0; t < Tq_; ++t) a += base[t * VK_];
        S[cjl][0][v] = a;
        float run = a;
        for (int l = 1; l < NL; ++l) {
            run += base[(251 + l) * VK_] - base[(l - 1) * VK_];
            S[cjl][l][v] = run;
        }
    }
    __syncthreads();
    for (int e = threadIdx.x; e < S_ * NL * VK_; e += 128) {
        int s = e / (NL * VK_), r = e % (NL * VK_), l = r / VK_, v = r % VK_;
        float a = wb[s * 64 + cjg * 2] * S[0][l][v] + wb[s * 64 + cjg * 2 + 1] * S[1][l][v];
        if (cjg == 0) a += (float)Tq_ * cb[s];
        atomicAdd(&kbsum[((size_t)(n * 4 + s) * NL + l) * VK_ + v], a);
    }
}

// ---------------------------------------------------------------- K3: MFMA scores
// v4: 12-t chunks, depth-1 counted vmcnt, 62KB dbuf, XCD swizzle, setprio.
__global__ __launch_bounds__(256)
void k3_mfma(const short* __restrict__ xqT, const short* __restrict__ kqT,
             float* __restrict__ partial) {
    int lin = blockIdx.x + 16 * blockIdx.y;   // 0..511
    int grp = lin & 7;                        // XCD
    int idx = lin >> 3;                       // 0..63
    int slice = grp + 8 * (idx >> 3);         // n*8+g, 8 slices per XCD
    int sub = idx & 7;                        // s*2+half
    int n = slice >> 3, g = slice & 7;
    int s = sub >> 1, half = sub & 1;
    int ns = n * 4 + s;
    int gx = g * 2 + half;                    // partial slice index 0..15
    __shared__ __align__(16) short sbuf[2][15872];   // 2 x 31744B = 62KB
    int tid = threadIdx.x;
    int wave = tid >> 6, lane = tid & 63;
    int q = lane >> 5, nl = lane & 31;
    int n1 = wave * 64 + nl, n2 = n1 + 32;
    int nc1 = min(n1, 249), nc2 = min(n2, 249);
    int l1 = nc1 / VK_, v1 = nc1 % VK_;
    int l2 = nc2 / VK_, v2 = nc2 % VK_;
    int bo1 = ((q + l1) * VK_ + v1) * 8;
    int bo2 = ((q + l2) * VK_ + v2) * 8;
    int ao = (q * 96 + nl) * 8;
    f32x16 acc[6];
#pragma unroll
    for (int i = 0; i < 6; ++i)
#pragma unroll
        for (int r = 0; r < 16; ++r) acc[i][r] = 0.f;
    const short* asrc = xqT + (size_t)(n * 8 + g) * 256 * 768;
    const short* bsrc = kqT + (size_t)(ns * 8 + g) * 256 * 400;
    int c0 = half * 10, nch = half ? 11 : 10;
    int ncall = (wave == 3) ? 7 : 8;

    auto stage = [&](int buf, int ch) {
        int t0 = ch * 12;
        const short8* aS = (const short8*)(asrc + t0 * 768);
        const short8* bS = (const short8*)(bsrc + t0 * 400);
        char* db = (char*)(&sbuf[buf][0]);
        for (int it = 0; it < ncall; ++it) {
            int call = wave * 8 + it;            // 0..30 (call 31 never issued)
            int i = call * 64 + lane;            // linear lane-load index
            const void* gsrc = (i < 1152) ? (const void*)(aS + i)
                                          : (const void*)(bS + min(i - 1152, 799));
            gload_lds16(gsrc, db + call * 1024); // dst wave-uniform; HW adds lane*16
        }
    };

    stage(0, c0);
    for (int ci = 0; ci < nch; ++ci) {
        int cur = ci & 1;
        if (ci + 1 < nch) {
            stage(cur ^ 1, c0 + ci + 1);
            if (wave == 3) asm volatile("s_waitcnt vmcnt(7)" ::: "memory");
            else           asm volatile("s_waitcnt vmcnt(8)" ::: "memory");
        } else {
            asm volatile("s_waitcnt vmcnt(0)" ::: "memory");
        }
        __builtin_amdgcn_s_barrier();
        const short* xa  = &sbuf[cur][0];
        const short* kbs = &sbuf[cur][9216];     // B starts at byte 18432
        __builtin_amdgcn_s_setprio(1);
#pragma unroll
        for (int ts = 0; ts < 6; ++ts) {
            short8 a0 = *(const short8*)(xa + ao + ts * 1536);
            short8 a1 = *(const short8*)(xa + ao + 256 + ts * 1536);
            short8 a2 = *(const short8*)(xa + ao + 512 + ts * 1536);
            short8 b0 = *(const short8*)(kbs + bo1 + ts * 800);
            short8 b1 = *(const short8*)(kbs + bo2 + ts * 800);
            acc[0] = __builtin_amdgcn_mfma_f32_32x32x16_bf16(a0, b0, acc[0], 0, 0, 0);
            acc[1] = __builtin_amdgcn_mfma_f32_32x32x16_bf16(a1, b0, acc[1], 0, 0, 0);
            acc[2] = __builtin_amdgcn_mfma_f32_32x32x16_bf16(a2, b0, acc[2], 0, 0, 0);
            acc[3] = __builtin_amdgcn_mfma_f32_32x32x16_bf16(a0, b1, acc[3], 0, 0, 0);
            acc[4] = __builtin_amdgcn_mfma_f32_32x32x16_bf16(a1, b1, acc[4], 0, 0, 0);
            acc[5] = __builtin_amdgcn_mfma_f32_32x32x16_bf16(a2, b1, acc[5], 0, 0, 0);
        }
        __builtin_amdgcn_s_setprio(0);
        __builtin_amdgcn_s_barrier();            // protect buf[cur] before re-stage
    }
#pragma unroll
    for (int inb = 0; inb < 2; ++inb) {
        int ng = wave * 64 + inb * 32 + nl;
        if (ng < 250) {
            int l = ng / VK_, v = ng % VK_;
            float* pb = partial + ((((size_t)ns * 5 + l) * 90) * NSL + gx) * VK_ + v;
#pragma unroll
            for (int iu = 0; iu < 3; ++iu) {
#pragma unroll
                for (int r = 0; r < 16; ++r) {
                    int u2 = iu * 32 + (r & 3) + 8 * (r >> 2) + 4 * q;
                    if (u2 < 90) pb[(size_t)u2 * NSL * VK_] = acc[inb * 3 + iu][r];
                }
            }
        }
    }
}

// ---------------------------------------------------------------- K4: reduce slices + combine lags + softmax
__global__ __launch_bounds__(256)
void k4_softmax(const float* __restrict__ partial, const float* __restrict__ kbsum,
                bf16* __restrict__ att) {
    int ug = blockIdx.x;
    int ns = blockIdx.y;
    int u0 = ug * 15;
    __shared__ float sred[NL * 15 * VK_];
    for (int idx = threadIdx.x; idx < NL * 15 * VK_; idx += 256) {
        int l = idx / (15 * VK_), r = idx % (15 * VK_);
        int u2 = r / VK_, v = r % VK_;
        const float* p = partial + (((size_t)(ns * NL + l) * 90 + u0 + u2) * NSL) * VK_ + v;
        float a = 0.f;
#pragma unroll
        for (int sl = 0; sl < NSL; ++sl) a += p[sl * VK_];
        sred[idx] = a;
    }
    __syncthreads();
    if (threadIdx.x < 15) {
        int u2 = threadIdx.x;
        const float inv_scale = rsqrtf((float)(C_ * Tq_));
        float pv[VK_];
        float pmax = -1e30f;
#pragma unroll
        for (int v = 0; v < VK_; ++v) {
            float mx = -1e30f, mn = 0.f;
#pragma unroll
            for (int l = 0; l < NL; ++l) {
                float sl = (sred[(l * 15 + u2) * VK_ + v] + kbsum[((size_t)ns * NL + l) * VK_ + v]) * inv_scale;
                mx = fmaxf(mx, sl); mn += sl;
            }
            pv[v] = 0.5f * (mx + mn * (1.f / NL));
            pmax = fmaxf(pmax, pv[v]);
        }
        float sum = 0.f;
#pragma unroll
        for (int v = 0; v < VK_; ++v) { pv[v] = __expf(pv[v] - pmax); sum += pv[v]; }
        float inv = 1.f / sum;
#pragma unroll
        for (int v = 0; v < VK_; ++v)
            att[((size_t)ns * VQ_ + u0 + u2) * VK_ + v] = f2b(pv[v] * inv);
    }
}

// ---------------------------------------------------------------- K5: MFMA wv_pack
// v3: flipped operands (A = x_v fragment, B = Wos fragment) so C rows = (t,v);
// lane holds 4 consecutive v -> direct unconditional 8B stores, no LDS transpose.
__global__ __launch_bounds__(256)
void k5_mfma(const float* __restrict__ x_v, const short* __restrict__ WosA,
             short* __restrict__ wv_pack) {
    int tb = blockIdx.x, n = blockIdx.y;
    int t0 = tb * 2;
    __shared__ __align__(16) short Ab[8 * 256 * 8]; // 32KB (Wos, B operand)
    __shared__ __align__(16) short Bb[8 * 128 * 8]; // 16KB (x_v, A operand)
    __shared__ float xs[3200];       // 12.8KB
    int tid = threadIdx.x;
    int wave = tid >> 6, lane = tid & 63, q = lane >> 5, c32 = lane & 31;
    {
        const short8* Asrc = (const short8*)WosA;
#pragma unroll
        for (int it = 0; it < 8; ++it) {
            int call = wave * 8 + it;
            gload_lds16(Asrc + call * 64 + lane, (char*)Ab + call * 1024);
        }
    }
#pragma unroll
    for (int p = 0; p < 2; ++p) {
        for (int i4 = tid; i4 < 800; i4 += 256) {
            int cc = i4 / 25, o = i4 % 25;
            *(float4*)(&xs[cc * 100 + o * 4]) =
                *(const float4*)(x_v + ((size_t)(n * 64 + p * 32 + cc) * 256 + t0) * 50 + o * 4);
        }
        __syncthreads();
        for (int m = tid; m < 512; m += 256) {
            int kgl = m >> 7, c = m & 127, t = c >> 6, v = c & 63;
            short8 pk;
            if (v < VK_) {
#pragma unroll
                for (int j = 0; j < 8; ++j) pk[j] = f2bs(xs[(kgl * 8 + j) * 100 + t * 50 + v]);
            } else {
#pragma unroll
                for (int j = 0; j < 8; ++j) pk[j] = 0;
            }
            *(short8*)(Bb + ((p * 4 + kgl) * 128 + c) * 8) = pk;
        }
        __syncthreads();
    }
    asm volatile("s_waitcnt vmcnt(0)" ::: "memory");
    __builtin_amdgcn_s_barrier();
    // acc[m = (t,v) 32-row tile][nn2 = o 32-col tile within wave's 64 cols]
    f32x16 acc[4][2];
#pragma unroll
    for (int m = 0; m < 4; ++m)
#pragma unroll
        for (int nn2 = 0; nn2 < 2; ++nn2)
#pragma unroll
            for (int r = 0; r < 16; ++r) acc[m][nn2][r] = 0.f;
#pragma unroll
    for (int ks = 0; ks < 4; ++ks) {
        int kg = 2 * ks + q;
        short8 bw0 = *(const short8*)(Ab + (kg * 256 + wave * 64 + c32) * 8);
        short8 bw1 = *(const short8*)(Ab + (kg * 256 + wave * 64 + 32 + c32) * 8);
#pragma unroll
        for (int m = 0; m < 4; ++m) {
            short8 ax = *(const short8*)(Bb + (kg * 128 + m * 32 + c32) * 8);
            acc[m][0] = __builtin_amdgcn_mfma_f32_32x32x16_bf16(ax, bw0, acc[m][0], 0, 0, 0);
            acc[m][1] = __builtin_amdgcn_mfma_f32_32x32x16_bf16(ax, bw1, acc[m][1], 0, 0, 0);
        }
    }
    // stores: row = (t,v): t = t0 + (m>>1), v = (m&1)*32 + 8*rq + 4q + rr.
    // wv_pack slot = s*8 + (v>>3) with s = wave; within slot: o*8 + (v&7).
    // All stores unconditional (v>=50 slots are zero and att-masked in k6).
#pragma unroll
    for (int m = 0; m < 4; ++m)
#pragma unroll
        for (int nn2 = 0; nn2 < 2; ++nn2) {
            int o = nn2 * 32 + c32;
            int t = t0 + (m >> 1);
            f32x16 A = acc[m][nn2];
            size_t base = (((size_t)(n * 256 + t) * 32) + wave * 8 + (m & 1) * 4) * 512 + o * 8 + 4 * q;
#pragma unroll
            for (int rq = 0; rq < 4; ++rq) {
                short4v pk;
#pragma unroll
                for (int rr = 0; rr < 4; ++rr) pk[rr] = f2bs(A[rq * 4 + rr]);
                *(short4v*)(wv_pack + base + (size_t)rq * 512) = pk;
            }
        }
}

// ---------------------------------------------------------------- K6: MFMA y-path, K=256
__global__ __launch_bounds__(256)
void k6_mfma(const bf16* __restrict__ att, const short* __restrict__ wv_pack,
             const float* __restrict__ bos, bf16* __restrict__ out_pre) {
    int tc = blockIdx.x, n = blockIdx.y;
    __shared__ __align__(16) short att_p[32 * 96 * 8]; // 48KB [g][u][j8]
    __shared__ float bos_s[64];
    int tid = threadIdx.x;
    if (tid < 64) bos_s[tid] = bos[tid];
    for (int m = tid; m < 96 * 256; m += 256) {
        int u2 = m >> 8, k = m & 255;
        int s = k >> 6, vs = k & 63;
        short val = 0;
        if (u2 < 90 && vs < VK_) {
            bf16 h = att[((size_t)(n * 4 + s) * 90 + u2) * VK_ + vs];
            val = *reinterpret_cast<short*>(&h);
        }
        att_p[((k >> 3) * 96 + u2) * 8 + (k & 7)] = val;
    }
    __syncthreads();
    int wave = tid >> 6, lane = tid & 63;
    int q = lane >> 5, c = lane & 31;
    int t = tc * 4 + wave;
    f32x16 acc[6];
#pragma unroll
    for (int ot = 0; ot < 2; ++ot)
#pragma unroll
        for (int r = 0; r < 16; ++r) {
            float b = bos_s[ot * 32 + (r & 3) + 8 * (r >> 2) + 4 * q];
            acc[ot * 3 + 0][r] = b; acc[ot * 3 + 1][r] = b; acc[ot * 3 + 2][r] = b;
        }
    const short* wbase = wv_pack + (size_t)(n * 256 + t) * (32 * 512);
#pragma unroll
    for (int st = 0; st < 16; ++st) {
        int gq = 2 * st + q;
        short8 a0 = *(const short8*)(wbase + (gq * 64 + c) * 8);
        short8 a1 = *(const short8*)(wbase + (gq * 64 + 32 + c) * 8);
        short8 b0 = *(const short8*)(att_p + (gq * 96 + c) * 8);
        short8 b1 = *(const short8*)(att_p + (gq * 96 + 32 + c) * 8);
        short8 b2 = *(const short8*)(att_p + (gq * 96 + 64 + c) * 8);
        acc[0] = __builtin_amdgcn_mfma_f32_32x32x16_bf16(a0, b0, acc[0], 0, 0, 0);
        acc[1] = __builtin_amdgcn_mfma_f32_32x32x16_bf16(a0, b1, acc[1], 0, 0, 0);
        acc[2] = __builtin_amdgcn_mfma_f32_32x32x16_bf16(a0, b2, acc[2], 0, 0, 0);
        acc[3] = __builtin_amdgcn_mfma_f32_32x32x16_bf16(a1, b0, acc[3], 0, 0, 0);
        acc[4] = __builtin_amdgcn_mfma_f32_32x32x16_bf16(a1, b1, acc[4], 0, 0, 0);
        acc[5] = __builtin_amdgcn_mfma_f32_32x32x16_bf16(a1, b2, acc[5], 0, 0, 0);
    }
#pragma unroll
    for (int ot = 0; ot < 2; ++ot)
#pragma unroll
        for (int ut = 0; ut < 3; ++ut) {
            int u2 = ut * 32 + c;
            if (u2 < 90) {
                f32x16 A = acc[ot * 3 + ut];
#pragma unroll
                for (int r = 0; r < 16; ++r) {
                    int o = ot * 32 + (r & 3) + 8 * (r >> 2) + 4 * q;
                    out_pre[((size_t)(n * 64 + o) * 256 + t) * 90 + u2] = f2b(A[r]);
                }
            }
        }
}

// ---------------------------------------------------------------- K7: MFMA down conv
__global__ __launch_bounds__(256)
void k7_mfma(const float* __restrict__ X, const float* __restrict__ W,
             const float* __restrict__ bias, bf16* __restrict__ out) {
    int cb = blockIdx.x, n = blockIdx.y;
    int col0 = cb * 256;
    __shared__ __align__(16) short A[8 * 64 * 8];  // 8KB
    __shared__ __align__(16) short B[8 * 256 * 8]; // 32KB
    __shared__ float bias_s[64];
    __shared__ float xs[2048];                     // 8KB: [cl][256]
    int tid = threadIdx.x;
    if (tid < 64) bias_s[tid] = bias[tid];
    for (int idx = tid; idx < 4096; idx += 256) {
        int o = idx >> 6, k = idx & 63;
        A[((k >> 3) * 64 + o) * 8 + (k & 7)] = f2bs(W[o * 64 + k]);
    }
#pragma unroll
    for (int p = 0; p < 8; ++p) {
        for (int i4 = tid; i4 < 512; i4 += 256) {
            int cl = i4 >> 6, o = i4 & 63;
            *(float4*)(&xs[cl * 256 + o * 4]) =
                *(const float4*)(X + (size_t)(n * 64 + p * 8 + cl) * COLS + col0 + o * 4);
        }
        __syncthreads();
        {
            short8 pk;
#pragma unroll
            for (int j = 0; j < 8; ++j) pk[j] = f2bs(xs[j * 256 + tid]);
            *(short8*)(B + (p * 256 + tid) * 8) = pk;
        }
        __syncthreads();
    }
    int wave = tid >> 6, lane = tid & 63, q = lane >> 5, c32 = lane & 31;
    f32x16 acc[2][2];
#pragma unroll
    for (int mt = 0; mt < 2; ++mt)
#pragma unroll
        for (int r = 0; r < 16; ++r) {
            float b = bias_s[mt * 32 + (r & 3) + 8 * (r >> 2) + 4 * q];
            acc[mt][0][r] = b; acc[mt][1][r] = b;
        }
#pragma unroll
    for (int ks = 0; ks < 4; ++ks) {
        int kg = 2 * ks + q;
        short8 a0 = *(const short8*)(A + (kg * 64 + c32) * 8);
        short8 a1 = *(const short8*)(A + (kg * 64 + 32 + c32) * 8);
#pragma unroll
        for (int i = 0; i < 2; ++i) {
            short8 b = *(const short8*)(B + (kg * 256 + (wave * 2 + i) * 32 + c32) * 8);
            acc[0][i] = __builtin_amdgcn_mfma_f32_32x32x16_bf16(a0, b, acc[0][i], 0, 0, 0);
            acc[1][i] = __builtin_amdgcn_mfma_f32_32x32x16_bf16(a1, b, acc[1][i], 0, 0, 0);
        }
    }
#pragma unroll
    for (int mt = 0; mt < 2; ++mt)
#pragma unroll
        for (int i = 0; i < 2; ++i) {
            int col = col0 + (wave * 2 + i) * 32 + c32;
#pragma unroll
            for (int r = 0; r < 16; ++r) {
                int o = mt * 32 + (r & 3) + 8 * (r >> 2) + 4 * q;
                out[(size_t)(n * 64 + o) * COLS + col] = f2b(acc[mt][i][r]);
            }
        }
}

// ---------------------------------------------------------------- K8: per-channel sum/sumsq (vectorized short8)
__global__ __launch_bounds__(256)
void k8_stats(const bf16* __restrict__ out_pre, const bf16* __restrict__ d_pre,
              float* __restrict__ stats) {
    int path = blockIdx.x >> 9;
    int b = blockIdx.x & 511;
    int o = b >> 3, n = b & 7;
    const bf16* p = (path ? d_pre : out_pre) + ((size_t)n * C_ + o) * COLS;
    float s = 0.f, sq = 0.f;
    for (int i8 = threadIdx.x; i8 < COLS / 8; i8 += 256) {
        short8 v8 = *(const short8*)(p + i8 * 8);
#pragma unroll
        for (int j = 0; j < 8; ++j) {
            float x = s2f(v8[j]);
            s += x; sq += x * x;
        }
    }
#pragma unroll
    for (int off = 32; off > 0; off >>= 1) {
        s  += __shfl_down(s, off, 64);
        sq += __shfl_down(sq, off, 64);
    }
    __shared__ float red[8];
    int wid = threadIdx.x >> 6, lane = threadIdx.x & 63;
    if (lane == 0) { red[wid * 2] = s; red[wid * 2 + 1] = sq; }
    __syncthreads();
    if (threadIdx.x == 0) {
        float S = 0.f, Q = 0.f;
        for (int w2 = 0; w2 < 4; ++w2) { S += red[w2 * 2]; Q += red[w2 * 2 + 1]; }
        atomicAdd(&stats[path * 128 + o * 2], S);
        atomicAdd(&stats[path * 128 + o * 2 + 1], Q);
    }
}

// ---------------------------------------------------------------- K9: BN + BN + add + leaky relu (vectorized)
__global__ __launch_bounds__(256)
void k9_final(const bf16* __restrict__ out_pre, const bf16* __restrict__ d_pre,
              const float* __restrict__ stats,
              const float* __restrict__ gamma_out, const float* __restrict__ beta_out,
              const float* __restrict__ gamma_down, const float* __restrict__ beta_down,
              float* __restrict__ out) {
    const float invM = 1.f / ((float)N_ * COLS);
    size_t total8 = (size_t)N_ * C_ * COLS / 8;   // 1474560
    size_t stride = (size_t)gridDim.x * blockDim.x;
    for (size_t i8 = (size_t)blockIdx.x * blockDim.x + threadIdx.x; i8 < total8; i8 += stride) {
        size_t idx = i8 * 8;
        int o = (int)((idx / COLS) % C_);         // COLS % 8 == 0 -> o uniform over pack
        float my = stats[o * 2] * invM;
        float vy = stats[o * 2 + 1] * invM - my * my;
        float md = stats[128 + o * 2] * invM;
        float vd = stats[128 + o * 2 + 1] * invM - md * md;
        float ay = rsqrtf(vy + EPSf) * gamma_out[o];
        float by = beta_out[o] - my * ay;
        float ad = rsqrtf(vd + EPSf) * gamma_down[o];
        float bd = beta_down[o] - md * ad;
        short8 y8 = *(const short8*)(out_pre + idx);
        short8 d8 = *(const short8*)(d_pre + idx);
        float rr[8];
#pragma unroll
        for (int j = 0; j < 8; ++j) {
            float r = (s2f(y8[j]) * ay + by) + (s2f(d8[j]) * ad + bd);
            rr[j] = r > 0.f ? r : 0.1f * r;
        }
        *(float4*)(out + idx)     = make_float4(rr[0], rr[1], rr[2], rr[3]);
        *(float4*)(out + idx + 4) = make_float4(rr[4], rr[5], rr[6], rr[7]);
    }
}

// ----------------------------------------------------------------
extern "C" void kernel_launch(void* const* d_in, const int* in_sizes, int n_in,
                              void* d_out, int out_size, void* d_ws, size_t ws_size,
                              hipStream_t stream) {
    (void)in_sizes; (void)n_in; (void)out_size; (void)ws_size;
    const float* x_q  = (const float*)d_in[0];
    const float* x_k  = (const float*)d_in[1];
    const float* x_v  = (const float*)d_in[2];
    const float* Wq   = (const float*)d_in[3];
    const float* bq   = (const float*)d_in[4];
    const float* Wk   = (const float*)d_in[5];
    const float* bk   = (const float*)d_in[6];
    const float* Wv   = (const float*)d_in[7];
    const float* bv   = (const float*)d_in[8];
    const float* Wout = (const float*)d_in[9];
    const float* bout = (const float*)d_in[10];
    const float* gamma_out  = (const float*)d_in[11];
    const float* beta_out   = (const float*)d_in[12];
    const float* Wdown = (const float*)d_in[13];
    const float* bdown = (const float*)d_in[14];
    const float* gamma_down = (const float*)d_in[15];
    const float* beta_down  = (const float*)d_in[16];

    char* w = (char*)d_ws;
    size_t off = 0;
    auto nxt = [&](size_t bytes) {
        char* p = w + off;
        off += (bytes + 255) & ~(size_t)255;
        return p;
    };
    // small persistent buffers
    short* MtA   = (short*)nxt((size_t)8 * 256 * 8 * 2);   // 32KB
    float* bMp   = (float*)nxt(256 * 4);
    float* wbp   = (float*)nxt((size_t)S_ * C_ * 4);
    float* cbp   = (float*)nxt((size_t)S_ * 4);
    short* WosA  = (short*)nxt((size_t)8 * 256 * 8 * 2);   // 32KB
    float* bos   = (float*)nxt((size_t)C_ * 4);
    float* kbsum = (float*)nxt((size_t)N_ * S_ * NL * VK_ * 4); // 32KB
    bf16*  att   = (bf16*)nxt((size_t)N_ * S_ * VQ_ * VK_ * 2);
    float* stats = (float*)nxt(256 * 4);
    // regionA: xqT (k0c->k3) then out_pre (k6->k8,k9)
    char* regionA = nxt((size_t)N_ * 8 * T_ * 96 * 8 * 2);            // 25.2MB
    short* xqT    = (short*)regionA;
    bf16*  out_pre = (bf16*)regionA;
    // regionB: kqT (k1->k3) then d_pre (k7->k8,k9)
    char* regionB = nxt((size_t)N_ * S_ * 8 * T_ * VK_ * 8 * 2);      // 52.4MB
    short* kqT   = (short*)regionB;
    bf16*  d_pre = (bf16*)regionB;
    // regionC: partial (k3->k4) then wv_pack (k5->k6)
    char* regionC = nxt((size_t)N_ * T_ * 32 * 512 * 2);              // 67.1MB
    float* partial = (float*)regionC;
    short* wv_pack = (short*)regionC;

    hipMemsetAsync(stats, 0, 256 * 4, stream);
    hipMemsetAsync(kbsum, 0, (size_t)N_ * S_ * NL * VK_ * 4, stream);

    k0_precompute<<<S_ * C_, 64, 0, stream>>>(Wq, bq, Wk, bk, MtA, bMp, wbp, cbp);
    k0b_wos<<<C_, 256, 0, stream>>>(Wout, bout, Wv, bv, WosA, bos);
    k0c_xqt<<<dim3(64, 8, N_), 256, 0, stream>>>(x_q, xqT);
    k1_mfma<<<dim3(128, N_), 256, 0, stream>>>(x_k, MtA, bMp, kqT);
    k3b_kbsum<<<dim3(32, N_), 128, 0, stream>>>(x_k, wbp, cbp, kbsum);
    k3_mfma<<<dim3(NSL, N_ * S_), 256, 0, stream>>>(xqT, kqT, partial);
    k4_softmax<<<dim3(6, N_ * S_), 256, 0, stream>>>(partial, kbsum, att);
    k5_mfma<<<dim3(128, N_), 256, 0, stream>>>(x_v, WosA, wv_pack);
    k6_mfma<<<dim3(T_ / 4, N_), 256, 0, stream>>>(att, wv_pack, bos, out_pre);
    k7_mfma<<<dim3(COLS / 256, N_), 256, 0, stream>>>(x_q, Wdown, bdown, d_pre);
    k8_stats<<<1024, 256, 0, stream>>>(out_pre, d_pre, stats);
    k9_final<<<2880, 256, 0, stream>>>(out_pre, d_pre, stats, gamma_out, beta_out,
                                       gamma_down, beta_down, (float*)d_out);
}

// Round 7
// 368.394 us; speedup vs baseline: 1.0949x; 1.0049x over previous
//
#include <hip/hip_runtime.h>
#include <hip/hip_bf16.h>

typedef __hip_bfloat16 bf16;
typedef __attribute__((ext_vector_type(4))) short short4v;
typedef __attribute__((ext_vector_type(8))) short short8;
typedef __attribute__((ext_vector_type(16))) float f32x16;

__device__ __forceinline__ float b2f(bf16 x) { return __bfloat162float(x); }
__device__ __forceinline__ bf16  f2b(float x) { return __float2bfloat16(x); }
__device__ __forceinline__ short f2bs(float x) {
    bf16 h = __float2bfloat16(x);
    return *reinterpret_cast<short*>(&h);
}
__device__ __forceinline__ float s2f(short s) {
    bf16 h; *reinterpret_cast<short*>(&h) = s; return __bfloat162float(h);
}
// async global->LDS, 16B per lane; dst must be wave-uniform (HW adds lane*16)
__device__ __forceinline__ void gload_lds16(const void* g, void* l) {
    __builtin_amdgcn_global_load_lds(
        (const __attribute__((address_space(1))) void*)g,
        (__attribute__((address_space(3))) void*)l, 16, 0, 0);
}

constexpr int N_ = 8, C_ = 64, T_ = 256, VQ_ = 90, VK_ = 50, S_ = 4, L_ = 4;
constexpr int Tq_ = T_ - L_;     // 252
constexpr int NL  = L_ + 1;      // 5 lags
constexpr int COLS = T_ * VQ_;   // 23040
constexpr float EPSf = 1e-5f;
constexpr int NSL = 16;          // score partial K-slices

// ---------------------------------------------------------------- K0: fold Wq into key side
__global__ __launch_bounds__(64)
void k0_precompute(const float* __restrict__ Wq, const float* __restrict__ bq,
                   const float* __restrict__ Wk, const float* __restrict__ bk,
                   short* __restrict__ MtA, float* __restrict__ bMp,
                   float* __restrict__ wb, float* __restrict__ cb) {
    int s  = blockIdx.x >> 6;
    int ci = blockIdx.x & 63;
    int cj = threadIdx.x;
    float m = 0.f;
    for (int c = 0; c < C_; ++c)
        m += Wq[(s * C_ + c) * C_ + ci] * Wk[(s * C_ + c) * C_ + cj];
    MtA[((cj >> 3) * 256 + s * C_ + ci) * 8 + (cj & 7)] = f2bs(m);
    if (cj == 0) {
        float v = 0.f;
        for (int c = 0; c < C_; ++c)
            v += Wq[(s * C_ + c) * C_ + ci] * bk[s * C_ + c];
        bMp[s * C_ + ci] = v;
    }
    if (ci == 0) {
        float v = 0.f;
        for (int c = 0; c < C_; ++c)
            v += bq[s * C_ + c] * Wk[(s * C_ + c) * C_ + cj];
        wb[s * C_ + cj] = v;
        if (cj == 0) {
            float v2 = 0.f;
            for (int c = 0; c < C_; ++c)
                v2 += bq[s * C_ + c] * bk[s * C_ + c];
            cb[s] = v2;
        }
    }
}

// ---------------------------------------------------------------- K0b: fold Wout into Wv
__global__ __launch_bounds__(256)
void k0b_wos(const float* __restrict__ Wout, const float* __restrict__ bout,
             const float* __restrict__ Wv, const float* __restrict__ bv,
             short* __restrict__ WosA, float* __restrict__ bos) {
    int cj = blockIdx.x;
    __shared__ float wvcol[C_];
    if (threadIdx.x < C_) wvcol[threadIdx.x] = Wv[threadIdx.x * C_ + cj];
    __syncthreads();
    int p = threadIdx.x;       // p = s*64 + o
    int s = p >> 6, o = p & 63;
    float acc = 0.f;
    for (int c = 0; c < C_; ++c)
        acc += Wout[o * (S_ * C_) + s * C_ + c] * wvcol[c];
    WosA[((cj >> 3) * 256 + p) * 8 + (cj & 7)] = f2bs(acc);
    if (cj == 0 && p < C_) {
        float a = bout[p];
        for (int k = 0; k < S_ * C_; ++k)
            a += Wout[p * (S_ * C_) + k] * bv[k & 63];
        bos[p] = a;
    }
}

// ---------------------------------------------------------------- K0c: xqT[n][g][t][u96][cc8] bf16
__global__ __launch_bounds__(256)
void k0c_xqt(const float* __restrict__ xq, short* __restrict__ xqT) {
    int tt = blockIdx.x;            // 64 tiles of 4 t
    int g  = blockIdx.y;
    int n  = blockIdx.z;
    int t0 = tt * 4;
    __shared__ float lds[8 * 360];  // [c][t*90+u], 11.5KB
    int tid = threadIdx.x;
    const float* src = xq + ((size_t)(n * 64 + g * 8) * 256 + t0) * 90;
#pragma unroll
    for (int i = tid; i < 720; i += 256) {
        int c = i / 90, r = i % 90;
        float4 v = *(const float4*)(src + (size_t)c * 23040 + r * 4);
        *(float4*)(&lds[c * 360 + r * 4]) = v;
    }
    __syncthreads();
    for (int e = tid; e < 4 * 96; e += 256) {
        int t = e / 96, u = e % 96;
        short8 pk;
#pragma unroll
        for (int j = 0; j < 8; ++j)
            pk[j] = (u < 90) ? f2bs(lds[j * 360 + t * 90 + u]) : (short)0;
        *(short8*)(xqT + (((size_t)(n * 8 + g) * 256 + t0 + t) * 96 + u) * 8) = pk;
    }
}

// ---------------------------------------------------------------- K1: MFMA kq = Mt @ x_k + bM -> kqT
// v3: direct dwordx2 epilogue (lane holds 4 consecutive ci), no LDS transpose.
__global__ __launch_bounds__(256)
void k1_mfma(const float* __restrict__ x_k, const short* __restrict__ MtA,
             const float* __restrict__ bMp, short* __restrict__ kqT) {
    int tb = blockIdx.x, n = blockIdx.y;
    int t0 = tb * 2;
    __shared__ __align__(16) short Ab[8 * 256 * 8]; // 32KB
    __shared__ __align__(16) short Bb[8 * 128 * 8]; // 16KB
    __shared__ float bmp_s[256];
    __shared__ float xs[3200];       // 12.8KB: [c32][100] = 32 ch x (2t x 50v)
    int tid = threadIdx.x;
    int wave = tid >> 6, lane = tid & 63, q = lane >> 5, c32 = lane & 31;
    if (tid < 256) bmp_s[tid] = bMp[tid];
    // A-stage via async global->LDS (MtA is L2-resident; 32 calls x 1KB)
    {
        const short8* Asrc = (const short8*)MtA;
#pragma unroll
        for (int it = 0; it < 8; ++it) {
            int call = wave * 8 + it;
            gload_lds16(Asrc + call * 64 + lane, (char*)Ab + call * 1024);
        }
    }
#pragma unroll
    for (int p = 0; p < 2; ++p) {
        for (int i4 = tid; i4 < 800; i4 += 256) {
            int cc = i4 / 25, o = i4 % 25;
            *(float4*)(&xs[cc * 100 + o * 4]) =
                *(const float4*)(x_k + ((size_t)(n * 64 + p * 32 + cc) * 256 + t0) * 50 + o * 4);
        }
        __syncthreads();
        for (int m = tid; m < 512; m += 256) {
            int kgl = m >> 7, c = m & 127, t = c >> 6, v = c & 63;
            short8 pk;
            if (v < VK_) {
#pragma unroll
                for (int j = 0; j < 8; ++j) pk[j] = f2bs(xs[(kgl * 8 + j) * 100 + t * 50 + v]);
            } else {
#pragma unroll
                for (int j = 0; j < 8; ++j) pk[j] = 0;
            }
            *(short8*)(Bb + ((p * 4 + kgl) * 128 + c) * 8) = pk;
        }
        __syncthreads();
    }
    asm volatile("s_waitcnt vmcnt(0)" ::: "memory");  // A-stage drained
    __builtin_amdgcn_s_barrier();
    f32x16 acc[2][4];
#pragma unroll
    for (int mt = 0; mt < 2; ++mt) {
#pragma unroll
        for (int r = 0; r < 16; ++r) {
            float b = bmp_s[wave * 64 + mt * 32 + (r & 3) + 8 * (r >> 2) + 4 * q];
#pragma unroll
            for (int nt = 0; nt < 4; ++nt) acc[mt][nt][r] = b;
        }
    }
#pragma unroll
    for (int ks = 0; ks < 4; ++ks) {
        int kg = 2 * ks + q;
        short8 a0 = *(const short8*)(Ab + (kg * 256 + wave * 64 + c32) * 8);
        short8 a1 = *(const short8*)(Ab + (kg * 256 + wave * 64 + 32 + c32) * 8);
#pragma unroll
        for (int nt = 0; nt < 4; ++nt) {
            short8 b = *(const short8*)(Bb + (kg * 128 + nt * 32 + c32) * 8);
            acc[0][nt] = __builtin_amdgcn_mfma_f32_32x32x16_bf16(a0, b, acc[0][nt], 0, 0, 0);
            acc[1][nt] = __builtin_amdgcn_mfma_f32_32x32x16_bf16(a1, b, acc[1][nt], 0, 0, 0);
        }
    }
    // direct stores: lane holds col (t,v); rows = 4-consecutive ci per rq group.
    int ns = n * 4 + wave;
#pragma unroll
    for (int mt = 0; mt < 2; ++mt)
#pragma unroll
        for (int nt = 0; nt < 4; ++nt) {
            int t = nt >> 1, v = (nt & 1) * 32 + c32;
            if (v < VK_) {
                f32x16 A = acc[mt][nt];
#pragma unroll
                for (int rq = 0; rq < 4; ++rq) {
                    short4v pk;
#pragma unroll
                    for (int rr = 0; rr < 4; ++rr) pk[rr] = f2bs(A[rq * 4 + rr]);
                    *(short4v*)(kqT + ((((size_t)(ns * 8 + mt * 4 + rq)) * 256 + t0 + t) * VK_ + v) * 8 + 4 * q) = pk;
                }
            }
        }
}

// ---------------------------------------------------------------- K3b: kbsum from x_k sliding sums
__global__ __launch_bounds__(128)
void k3b_kbsum(const float* __restrict__ x_k, const float* __restrict__ wb,
               const float* __restrict__ cb, float* __restrict__ kbsum) {
    int cjg = blockIdx.x;  // 32 groups of 2 cj
    int n = blockIdx.y;
    __shared__ float S[2][NL][VK_];
    for (int pr = threadIdx.x; pr < 2 * VK_; pr += 128) {
        int cjl = pr / VK_, v = pr % VK_;
        const float* base = x_k + ((size_t)(n * 64 + cjg * 2 + cjl) * 256) * VK_ + v;
        float a = 0.f;
        for (int t = 0; t < Tq_; ++t) a += base[t * VK_];
        S[cjl][0][v] = a;
        float run = a;
        for (int l = 1; l < NL; ++l) {
            run += base[(251 + l) * VK_] - base[(l - 1) * VK_];
            S[cjl][l][v] = run;
        }
    }
    __syncthreads();
    for (int e = threadIdx.x; e < S_ * NL * VK_; e += 128) {
        int s = e / (NL * VK_), r = e % (NL * VK_), l = r / VK_, v = r % VK_;
        float a = wb[s * 64 + cjg * 2] * S[0][l][v] + wb[s * 64 + cjg * 2 + 1] * S[1][l][v];
        if (cjg == 0) a += (float)Tq_ * cb[s];
        atomicAdd(&kbsum[((size_t)(n * 4 + s) * NL + l) * VK_ + v], a);
    }
}

// ---------------------------------------------------------------- K3: MFMA scores
// v5: v4 + dense partial layout [ns][l][gx][u][v] -> full-line coalesced
// epilogue stores (kills write-allocate RMW: FETCH was ~38MB of line fills).
__global__ __launch_bounds__(256)
void k3_mfma(const short* __restrict__ xqT, const short* __restrict__ kqT,
             float* __restrict__ partial) {
    int lin = blockIdx.x + 16 * blockIdx.y;   // 0..511
    int grp = lin & 7;                        // XCD
    int idx = lin >> 3;                       // 0..63
    int slice = grp + 8 * (idx >> 3);         // n*8+g, 8 slices per XCD
    int sub = idx & 7;                        // s*2+half
    int n = slice >> 3, g = slice & 7;
    int s = sub >> 1, half = sub & 1;
    int ns = n * 4 + s;
    int gx = g * 2 + half;                    // partial slice index 0..15
    __shared__ __align__(16) short sbuf[2][15872];   // 2 x 31744B = 62KB
    int tid = threadIdx.x;
    int wave = tid >> 6, lane = tid & 63;
    int q = lane >> 5, nl = lane & 31;
    int n1 = wave * 64 + nl, n2 = n1 + 32;
    int nc1 = min(n1, 249), nc2 = min(n2, 249);
    int l1 = nc1 / VK_, v1 = nc1 % VK_;
    int l2 = nc2 / VK_, v2 = nc2 % VK_;
    int bo1 = ((q + l1) * VK_ + v1) * 8;
    int bo2 = ((q + l2) * VK_ + v2) * 8;
    int ao = (q * 96 + nl) * 8;
    f32x16 acc[6];
#pragma unroll
    for (int i = 0; i < 6; ++i)
#pragma unroll
        for (int r = 0; r < 16; ++r) acc[i][r] = 0.f;
    const short* asrc = xqT + (size_t)(n * 8 + g) * 256 * 768;
    const short* bsrc = kqT + (size_t)(ns * 8 + g) * 256 * 400;
    int c0 = half * 10, nch = half ? 11 : 10;
    int ncall = (wave == 3) ? 7 : 8;

    auto stage = [&](int buf, int ch) {
        int t0 = ch * 12;
        const short8* aS = (const short8*)(asrc + t0 * 768);
        const short8* bS = (const short8*)(bsrc + t0 * 400);
        char* db = (char*)(&sbuf[buf][0]);
        for (int it = 0; it < ncall; ++it) {
            int call = wave * 8 + it;            // 0..30 (call 31 never issued)
            int i = call * 64 + lane;            // linear lane-load index
            const void* gsrc = (i < 1152) ? (const void*)(aS + i)
                                          : (const void*)(bS + min(i - 1152, 799));
            gload_lds16(gsrc, db + call * 1024); // dst wave-uniform; HW adds lane*16
        }
    };

    stage(0, c0);
    for (int ci = 0; ci < nch; ++ci) {
        int cur = ci & 1;
        if (ci + 1 < nch) {
            stage(cur ^ 1, c0 + ci + 1);
            if (wave == 3) asm volatile("s_waitcnt vmcnt(7)" ::: "memory");
            else           asm volatile("s_waitcnt vmcnt(8)" ::: "memory");
        } else {
            asm volatile("s_waitcnt vmcnt(0)" ::: "memory");
        }
        __builtin_amdgcn_s_barrier();
        const short* xa  = &sbuf[cur][0];
        const short* kbs = &sbuf[cur][9216];     // B starts at byte 18432
        __builtin_amdgcn_s_setprio(1);
#pragma unroll
        for (int ts = 0; ts < 6; ++ts) {
            short8 a0 = *(const short8*)(xa + ao + ts * 1536);
            short8 a1 = *(const short8*)(xa + ao + 256 + ts * 1536);
            short8 a2 = *(const short8*)(xa + ao + 512 + ts * 1536);
            short8 b0 = *(const short8*)(kbs + bo1 + ts * 800);
            short8 b1 = *(const short8*)(kbs + bo2 + ts * 800);
            acc[0] = __builtin_amdgcn_mfma_f32_32x32x16_bf16(a0, b0, acc[0], 0, 0, 0);
            acc[1] = __builtin_amdgcn_mfma_f32_32x32x16_bf16(a1, b0, acc[1], 0, 0, 0);
            acc[2] = __builtin_amdgcn_mfma_f32_32x32x16_bf16(a2, b0, acc[2], 0, 0, 0);
            acc[3] = __builtin_amdgcn_mfma_f32_32x32x16_bf16(a0, b1, acc[3], 0, 0, 0);
            acc[4] = __builtin_amdgcn_mfma_f32_32x32x16_bf16(a1, b1, acc[4], 0, 0, 0);
            acc[5] = __builtin_amdgcn_mfma_f32_32x32x16_bf16(a2, b1, acc[5], 0, 0, 0);
        }
        __builtin_amdgcn_s_setprio(0);
        __builtin_amdgcn_s_barrier();            // protect buf[cur] before re-stage
    }
    // dense epilogue: partial[((ns*5+l)*16+gx)][u][v] — block's region is
    // contiguous per (l): 90*50*4 = 18KB, full-line stores, no write-allocate.
#pragma unroll
    for (int inb = 0; inb < 2; ++inb) {
        int ng = wave * 64 + inb * 32 + nl;
        if (ng < 250) {
            int l = ng / VK_, v = ng % VK_;
            float* pb = partial + (((size_t)(ns * 5 + l) * NSL + gx) * 90) * VK_ + v;
#pragma unroll
            for (int iu = 0; iu < 3; ++iu) {
#pragma unroll
                for (int r = 0; r < 16; ++r) {
                    int u2 = iu * 32 + (r & 3) + 8 * (r >> 2) + 4 * q;
                    if (u2 < 90) pb[(size_t)u2 * VK_] = acc[inb * 3 + iu][r];
                }
            }
        }
    }
}

// ---------------------------------------------------------------- K4: reduce slices + combine lags + softmax
// v2: adapted to dense partial layout; gx-reduction reads are coalesced
// (lane-consecutive v, slice stride 18KB).
__global__ __launch_bounds__(256)
void k4_softmax(const float* __restrict__ partial, const float* __restrict__ kbsum,
                bf16* __restrict__ att) {
    int ug = blockIdx.x;
    int ns = blockIdx.y;
    int u0 = ug * 15;
    __shared__ float sred[NL * 15 * VK_];
    for (int idx = threadIdx.x; idx < NL * 15 * VK_; idx += 256) {
        int l = idx / (15 * VK_), r = idx % (15 * VK_);
        int u2 = r / VK_, v = r % VK_;
        const float* p = partial + ((size_t)(ns * NL + l) * NSL) * 90 * VK_
                         + (u0 + u2) * VK_ + v;
        float a = 0.f;
#pragma unroll
        for (int sl = 0; sl < NSL; ++sl) a += p[(size_t)sl * 90 * VK_];
        sred[idx] = a;
    }
    __syncthreads();
    if (threadIdx.x < 15) {
        int u2 = threadIdx.x;
        const float inv_scale = rsqrtf((float)(C_ * Tq_));
        float pv[VK_];
        float pmax = -1e30f;
#pragma unroll
        for (int v = 0; v < VK_; ++v) {
            float mx = -1e30f, mn = 0.f;
#pragma unroll
            for (int l = 0; l < NL; ++l) {
                float sl = (sred[(l * 15 + u2) * VK_ + v] + kbsum[((size_t)ns * NL + l) * VK_ + v]) * inv_scale;
                mx = fmaxf(mx, sl); mn += sl;
            }
            pv[v] = 0.5f * (mx + mn * (1.f / NL));
            pmax = fmaxf(pmax, pv[v]);
        }
        float sum = 0.f;
#pragma unroll
        for (int v = 0; v < VK_; ++v) { pv[v] = __expf(pv[v] - pmax); sum += pv[v]; }
        float inv = 1.f / sum;
#pragma unroll
        for (int v = 0; v < VK_; ++v)
            att[((size_t)ns * VQ_ + u0 + u2) * VK_ + v] = f2b(pv[v] * inv);
    }
}

// ---------------------------------------------------------------- K5: MFMA wv_pack
// v3: flipped operands (A = x_v fragment, B = Wos fragment) so C rows = (t,v);
// lane holds 4 consecutive v -> direct unconditional 8B stores, no LDS transpose.
__global__ __launch_bounds__(256)
void k5_mfma(const float* __restrict__ x_v, const short* __restrict__ WosA,
             short* __restrict__ wv_pack) {
    int tb = blockIdx.x, n = blockIdx.y;
    int t0 = tb * 2;
    __shared__ __align__(16) short Ab[8 * 256 * 8]; // 32KB (Wos, B operand)
    __shared__ __align__(16) short Bb[8 * 128 * 8]; // 16KB (x_v, A operand)
    __shared__ float xs[3200];       // 12.8KB
    int tid = threadIdx.x;
    int wave = tid >> 6, lane = tid & 63, q = lane >> 5, c32 = lane & 31;
    {
        const short8* Asrc = (const short8*)WosA;
#pragma unroll
        for (int it = 0; it < 8; ++it) {
            int call = wave * 8 + it;
            gload_lds16(Asrc + call * 64 + lane, (char*)Ab + call * 1024);
        }
    }
#pragma unroll
    for (int p = 0; p < 2; ++p) {
        for (int i4 = tid; i4 < 800; i4 += 256) {
            int cc = i4 / 25, o = i4 % 25;
            *(float4*)(&xs[cc * 100 + o * 4]) =
                *(const float4*)(x_v + ((size_t)(n * 64 + p * 32 + cc) * 256 + t0) * 50 + o * 4);
        }
        __syncthreads();
        for (int m = tid; m < 512; m += 256) {
            int kgl = m >> 7, c = m & 127, t = c >> 6, v = c & 63;
            short8 pk;
            if (v < VK_) {
#pragma unroll
                for (int j = 0; j < 8; ++j) pk[j] = f2bs(xs[(kgl * 8 + j) * 100 + t * 50 + v]);
            } else {
#pragma unroll
                for (int j = 0; j < 8; ++j) pk[j] = 0;
            }
            *(short8*)(Bb + ((p * 4 + kgl) * 128 + c) * 8) = pk;
        }
        __syncthreads();
    }
    asm volatile("s_waitcnt vmcnt(0)" ::: "memory");
    __builtin_amdgcn_s_barrier();
    f32x16 acc[4][2];
#pragma unroll
    for (int m = 0; m < 4; ++m)
#pragma unroll
        for (int nn2 = 0; nn2 < 2; ++nn2)
#pragma unroll
            for (int r = 0; r < 16; ++r) acc[m][nn2][r] = 0.f;
#pragma unroll
    for (int ks = 0; ks < 4; ++ks) {
        int kg = 2 * ks + q;
        short8 bw0 = *(const short8*)(Ab + (kg * 256 + wave * 64 + c32) * 8);
        short8 bw1 = *(const short8*)(Ab + (kg * 256 + wave * 64 + 32 + c32) * 8);
#pragma unroll
        for (int m = 0; m < 4; ++m) {
            short8 ax = *(const short8*)(Bb + (kg * 128 + m * 32 + c32) * 8);
            acc[m][0] = __builtin_amdgcn_mfma_f32_32x32x16_bf16(ax, bw0, acc[m][0], 0, 0, 0);
            acc[m][1] = __builtin_amdgcn_mfma_f32_32x32x16_bf16(ax, bw1, acc[m][1], 0, 0, 0);
        }
    }
#pragma unroll
    for (int m = 0; m < 4; ++m)
#pragma unroll
        for (int nn2 = 0; nn2 < 2; ++nn2) {
            int o = nn2 * 32 + c32;
            int t = t0 + (m >> 1);
            f32x16 A = acc[m][nn2];
            size_t base = (((size_t)(n * 256 + t) * 32) + wave * 8 + (m & 1) * 4) * 512 + o * 8 + 4 * q;
#pragma unroll
            for (int rq = 0; rq < 4; ++rq) {
                short4v pk;
#pragma unroll
                for (int rr = 0; rr < 4; ++rr) pk[rr] = f2bs(A[rq * 4 + rr]);
                *(short4v*)(wv_pack + base + (size_t)rq * 512) = pk;
            }
        }
}

// ---------------------------------------------------------------- K6: MFMA y-path, K=256
__global__ __launch_bounds__(256)
void k6_mfma(const bf16* __restrict__ att, const short* __restrict__ wv_pack,
             const float* __restrict__ bos, bf16* __restrict__ out_pre) {
    int tc = blockIdx.x, n = blockIdx.y;
    __shared__ __align__(16) short att_p[32 * 96 * 8]; // 48KB [g][u][j8]
    __shared__ float bos_s[64];
    int tid = threadIdx.x;
    if (tid < 64) bos_s[tid] = bos[tid];
    for (int m = tid; m < 96 * 256; m += 256) {
        int u2 = m >> 8, k = m & 255;
        int s = k >> 6, vs = k & 63;
        short val = 0;
        if (u2 < 90 && vs < VK_) {
            bf16 h = att[((size_t)(n * 4 + s) * 90 + u2) * VK_ + vs];
            val = *reinterpret_cast<short*>(&h);
        }
        att_p[((k >> 3) * 96 + u2) * 8 + (k & 7)] = val;
    }
    __syncthreads();
    int wave = tid >> 6, lane = tid & 63;
    int q = lane >> 5, c = lane & 31;
    int t = tc * 4 + wave;
    f32x16 acc[6];
#pragma unroll
    for (int ot = 0; ot < 2; ++ot)
#pragma unroll
        for (int r = 0; r < 16; ++r) {
            float b = bos_s[ot * 32 + (r & 3) + 8 * (r >> 2) + 4 * q];
            acc[ot * 3 + 0][r] = b; acc[ot * 3 + 1][r] = b; acc[ot * 3 + 2][r] = b;
        }
    const short* wbase = wv_pack + (size_t)(n * 256 + t) * (32 * 512);
#pragma unroll
    for (int st = 0; st < 16; ++st) {
        int gq = 2 * st + q;
        short8 a0 = *(const short8*)(wbase + (gq * 64 + c) * 8);
        short8 a1 = *(const short8*)(wbase + (gq * 64 + 32 + c) * 8);
        short8 b0 = *(const short8*)(att_p + (gq * 96 + c) * 8);
        short8 b1 = *(const short8*)(att_p + (gq * 96 + 32 + c) * 8);
        short8 b2 = *(const short8*)(att_p + (gq * 96 + 64 + c) * 8);
        acc[0] = __builtin_amdgcn_mfma_f32_32x32x16_bf16(a0, b0, acc[0], 0, 0, 0);
        acc[1] = __builtin_amdgcn_mfma_f32_32x32x16_bf16(a0, b1, acc[1], 0, 0, 0);
        acc[2] = __builtin_amdgcn_mfma_f32_32x32x16_bf16(a0, b2, acc[2], 0, 0, 0);
        acc[3] = __builtin_amdgcn_mfma_f32_32x32x16_bf16(a1, b0, acc[3], 0, 0, 0);
        acc[4] = __builtin_amdgcn_mfma_f32_32x32x16_bf16(a1, b1, acc[4], 0, 0, 0);
        acc[5] = __builtin_amdgcn_mfma_f32_32x32x16_bf16(a1, b2, acc[5], 0, 0, 0);
    }
#pragma unroll
    for (int ot = 0; ot < 2; ++ot)
#pragma unroll
        for (int ut = 0; ut < 3; ++ut) {
            int u2 = ut * 32 + c;
            if (u2 < 90) {
                f32x16 A = acc[ot * 3 + ut];
#pragma unroll
                for (int r = 0; r < 16; ++r) {
                    int o = ot * 32 + (r & 3) + 8 * (r >> 2) + 4 * q;
                    out_pre[((size_t)(n * 64 + o) * 256 + t) * 90 + u2] = f2b(A[r]);
                }
            }
        }
}

// ---------------------------------------------------------------- K7: MFMA down conv
__global__ __launch_bounds__(256)
void k7_mfma(const float* __restrict__ X, const float* __restrict__ W,
             const float* __restrict__ bias, bf16* __restrict__ out) {
    int cb = blockIdx.x, n = blockIdx.y;
    int col0 = cb * 256;
    __shared__ __align__(16) short A[8 * 64 * 8];  // 8KB
    __shared__ __align__(16) short B[8 * 256 * 8]; // 32KB
    __shared__ float bias_s[64];
    __shared__ float xs[2048];                     // 8KB: [cl][256]
    int tid = threadIdx.x;
    if (tid < 64) bias_s[tid] = bias[tid];
    for (int idx = tid; idx < 4096; idx += 256) {
        int o = idx >> 6, k = idx & 63;
        A[((k >> 3) * 64 + o) * 8 + (k & 7)] = f2bs(W[o * 64 + k]);
    }
#pragma unroll
    for (int p = 0; p < 8; ++p) {
        for (int i4 = tid; i4 < 512; i4 += 256) {
            int cl = i4 >> 6, o = i4 & 63;
            *(float4*)(&xs[cl * 256 + o * 4]) =
                *(const float4*)(X + (size_t)(n * 64 + p * 8 + cl) * COLS + col0 + o * 4);
        }
        __syncthreads();
        {
            short8 pk;
#pragma unroll
            for (int j = 0; j < 8; ++j) pk[j] = f2bs(xs[j * 256 + tid]);
            *(short8*)(B + (p * 256 + tid) * 8) = pk;
        }
        __syncthreads();
    }
    int wave = tid >> 6, lane = tid & 63, q = lane >> 5, c32 = lane & 31;
    f32x16 acc[2][2];
#pragma unroll
    for (int mt = 0; mt < 2; ++mt)
#pragma unroll
        for (int r = 0; r < 16; ++r) {
            float b = bias_s[mt * 32 + (r & 3) + 8 * (r >> 2) + 4 * q];
            acc[mt][0][r] = b; acc[mt][1][r] = b;
        }
#pragma unroll
    for (int ks = 0; ks < 4; ++ks) {
        int kg = 2 * ks + q;
        short8 a0 = *(const short8*)(A + (kg * 64 + c32) * 8);
        short8 a1 = *(const short8*)(A + (kg * 64 + 32 + c32) * 8);
#pragma unroll
        for (int i = 0; i < 2; ++i) {
            short8 b = *(const short8*)(B + (kg * 256 + (wave * 2 + i) * 32 + c32) * 8);
            acc[0][i] = __builtin_amdgcn_mfma_f32_32x32x16_bf16(a0, b, acc[0][i], 0, 0, 0);
            acc[1][i] = __builtin_amdgcn_mfma_f32_32x32x16_bf16(a1, b, acc[1][i], 0, 0, 0);
        }
    }
#pragma unroll
    for (int mt = 0; mt < 2; ++mt)
#pragma unroll
        for (int i = 0; i < 2; ++i) {
            int col = col0 + (wave * 2 + i) * 32 + c32;
#pragma unroll
            for (int r = 0; r < 16; ++r) {
                int o = mt * 32 + (r & 3) + 8 * (r >> 2) + 4 * q;
                out[(size_t)(n * 64 + o) * COLS + col] = f2b(acc[mt][i][r]);
            }
        }
}

// ---------------------------------------------------------------- K8: per-channel sum/sumsq (vectorized short8)
__global__ __launch_bounds__(256)
void k8_stats(const bf16* __restrict__ out_pre, const bf16* __restrict__ d_pre,
              float* __restrict__ stats) {
    int path = blockIdx.x >> 9;
    int b = blockIdx.x & 511;
    int o = b >> 3, n = b & 7;
    const bf16* p = (path ? d_pre : out_pre) + ((size_t)n * C_ + o) * COLS;
    float s = 0.f, sq = 0.f;
    for (int i8 = threadIdx.x; i8 < COLS / 8; i8 += 256) {
        short8 v8 = *(const short8*)(p + i8 * 8);
#pragma unroll
        for (int j = 0; j < 8; ++j) {
            float x = s2f(v8[j]);
            s += x; sq += x * x;
        }
    }
#pragma unroll
    for (int off = 32; off > 0; off >>= 1) {
        s  += __shfl_down(s, off, 64);
        sq += __shfl_down(sq, off, 64);
    }
    __shared__ float red[8];
    int wid = threadIdx.x >> 6, lane = threadIdx.x & 63;
    if (lane == 0) { red[wid * 2] = s; red[wid * 2 + 1] = sq; }
    __syncthreads();
    if (threadIdx.x == 0) {
        float S = 0.f, Q = 0.f;
        for (int w2 = 0; w2 < 4; ++w2) { S += red[w2 * 2]; Q += red[w2 * 2 + 1]; }
        atomicAdd(&stats[path * 128 + o * 2], S);
        atomicAdd(&stats[path * 128 + o * 2 + 1], Q);
    }
}

// ---------------------------------------------------------------- K9: BN + BN + add + leaky relu (vectorized)
__global__ __launch_bounds__(256)
void k9_final(const bf16* __restrict__ out_pre, const bf16* __restrict__ d_pre,
              const float* __restrict__ stats,
              const float* __restrict__ gamma_out, const float* __restrict__ beta_out,
              const float* __restrict__ gamma_down, const float* __restrict__ beta_down,
              float* __restrict__ out) {
    const float invM = 1.f / ((float)N_ * COLS);
    size_t total8 = (size_t)N_ * C_ * COLS / 8;   // 1474560
    size_t stride = (size_t)gridDim.x * blockDim.x;
    for (size_t i8 = (size_t)blockIdx.x * blockDim.x + threadIdx.x; i8 < total8; i8 += stride) {
        size_t idx = i8 * 8;
        int o = (int)((idx / COLS) % C_);         // COLS % 8 == 0 -> o uniform over pack
        float my = stats[o * 2] * invM;
        float vy = stats[o * 2 + 1] * invM - my * my;
        float md = stats[128 + o * 2] * invM;
        float vd = stats[128 + o * 2 + 1] * invM - md * md;
        float ay = rsqrtf(vy + EPSf) * gamma_out[o];
        float by = beta_out[o] - my * ay;
        float ad = rsqrtf(vd + EPSf) * gamma_down[o];
        float bd = beta_down[o] - md * ad;
        short8 y8 = *(const short8*)(out_pre + idx);
        short8 d8 = *(const short8*)(d_pre + idx);
        float rr[8];
#pragma unroll
        for (int j = 0; j < 8; ++j) {
            float r = (s2f(y8[j]) * ay + by) + (s2f(d8[j]) * ad + bd);
            rr[j] = r > 0.f ? r : 0.1f * r;
        }
        *(float4*)(out + idx)     = make_float4(rr[0], rr[1], rr[2], rr[3]);
        *(float4*)(out + idx + 4) = make_float4(rr[4], rr[5], rr[6], rr[7]);
    }
}

// ----------------------------------------------------------------
extern "C" void kernel_launch(void* const* d_in, const int* in_sizes, int n_in,
                              void* d_out, int out_size, void* d_ws, size_t ws_size,
                              hipStream_t stream) {
    (void)in_sizes; (void)n_in; (void)out_size; (void)ws_size;
    const float* x_q  = (const float*)d_in[0];
    const float* x_k  = (const float*)d_in[1];
    const float* x_v  = (const float*)d_in[2];
    const float* Wq   = (const float*)d_in[3];
    const float* bq   = (const float*)d_in[4];
    const float* Wk   = (const float*)d_in[5];
    const float* bk   = (const float*)d_in[6];
    const float* Wv   = (const float*)d_in[7];
    const float* bv   = (const float*)d_in[8];
    const float* Wout = (const float*)d_in[9];
    const float* bout = (const float*)d_in[10];
    const float* gamma_out  = (const float*)d_in[11];
    const float* beta_out   = (const float*)d_in[12];
    const float* Wdown = (const float*)d_in[13];
    const float* bdown = (const float*)d_in[14];
    const float* gamma_down = (const float*)d_in[15];
    const float* beta_down  = (const float*)d_in[16];

    char* w = (char*)d_ws;
    size_t off = 0;
    auto nxt = [&](size_t bytes) {
        char* p = w + off;
        off += (bytes + 255) & ~(size_t)255;
        return p;
    };
    // small persistent buffers
    short* MtA   = (short*)nxt((size_t)8 * 256 * 8 * 2);   // 32KB
    float* bMp   = (float*)nxt(256 * 4);
    float* wbp   = (float*)nxt((size_t)S_ * C_ * 4);
    float* cbp   = (float*)nxt((size_t)S_ * 4);
    short* WosA  = (short*)nxt((size_t)8 * 256 * 8 * 2);   // 32KB
    float* bos   = (float*)nxt((size_t)C_ * 4);
    float* kbsum = (float*)nxt((size_t)N_ * S_ * NL * VK_ * 4); // 32KB
    bf16*  att   = (bf16*)nxt((size_t)N_ * S_ * VQ_ * VK_ * 2);
    float* stats = (float*)nxt(256 * 4);
    // regionA: xqT (k0c->k3) then out_pre (k6->k8,k9)
    char* regionA = nxt((size_t)N_ * 8 * T_ * 96 * 8 * 2);            // 25.2MB
    short* xqT    = (short*)regionA;
    bf16*  out_pre = (bf16*)regionA;
    // regionB: kqT (k1->k3) then d_pre (k7->k8,k9)
    char* regionB = nxt((size_t)N_ * S_ * 8 * T_ * VK_ * 8 * 2);      // 52.4MB
    short* kqT   = (short*)regionB;
    bf16*  d_pre = (bf16*)regionB;
    // regionC: partial (k3->k4) then wv_pack (k5->k6)
    char* regionC = nxt((size_t)N_ * T_ * 32 * 512 * 2);              // 67.1MB
    float* partial = (float*)regionC;
    short* wv_pack = (short*)regionC;

    hipMemsetAsync(stats, 0, 256 * 4, stream);
    hipMemsetAsync(kbsum, 0, (size_t)N_ * S_ * NL * VK_ * 4, stream);

    k0_precompute<<<S_ * C_, 64, 0, stream>>>(Wq, bq, Wk, bk, MtA, bMp, wbp, cbp);
    k0b_wos<<<C_, 256, 0, stream>>>(Wout, bout, Wv, bv, WosA, bos);
    k0c_xqt<<<dim3(64, 8, N_), 256, 0, stream>>>(x_q, xqT);
    k1_mfma<<<dim3(128, N_), 256, 0, stream>>>(x_k, MtA, bMp, kqT);
    k3b_kbsum<<<dim3(32, N_), 128, 0, stream>>>(x_k, wbp, cbp, kbsum);
    k3_mfma<<<dim3(NSL, N_ * S_), 256, 0, stream>>>(xqT, kqT, partial);
    k4_softmax<<<dim3(6, N_ * S_), 256, 0, stream>>>(partial, kbsum, att);
    k5_mfma<<<dim3(128, N_), 256, 0, stream>>>(x_v, WosA, wv_pack);
    k6_mfma<<<dim3(T_ / 4, N_), 256, 0, stream>>>(att, wv_pack, bos, out_pre);
    k7_mfma<<<dim3(COLS / 256, N_), 256, 0, stream>>>(x_q, Wdown, bdown, d_pre);
    k8_stats<<<1024, 256, 0, stream>>>(out_pre, d_pre, stats);
    k9_final<<<2880, 256, 0, stream>>>(out_pre, d_pre, stats, gamma_out, beta_out,
                                       gamma_down, beta_down, (float*)d_out);
}

// Round 8
// 347.887 us; speedup vs baseline: 1.1594x; 1.0589x over previous
//
#include <hip/hip_runtime.h>
#include <hip/hip_bf16.h>

typedef __hip_bfloat16 bf16;
typedef __attribute__((ext_vector_type(4))) short short4v;
typedef __attribute__((ext_vector_type(8))) short short8;
typedef __attribute__((ext_vector_type(16))) float f32x16;

__device__ __forceinline__ float b2f(bf16 x) { return __bfloat162float(x); }
__device__ __forceinline__ bf16  f2b(float x) { return __float2bfloat16(x); }
__device__ __forceinline__ short f2bs(float x) {
    bf16 h = __float2bfloat16(x);
    return *reinterpret_cast<short*>(&h);
}
__device__ __forceinline__ float s2f(short s) {
    bf16 h; *reinterpret_cast<short*>(&h) = s; return __bfloat162float(h);
}
// async global->LDS, 16B per lane; dst must be wave-uniform (HW adds lane*16)
__device__ __forceinline__ void gload_lds16(const void* g, void* l) {
    __builtin_amdgcn_global_load_lds(
        (const __attribute__((address_space(1))) void*)g,
        (__attribute__((address_space(3))) void*)l, 16, 0, 0);
}

constexpr int N_ = 8, C_ = 64, T_ = 256, VQ_ = 90, VK_ = 50, S_ = 4, L_ = 4;
constexpr int Tq_ = T_ - L_;     // 252
constexpr int NL  = L_ + 1;      // 5 lags
constexpr int COLS = T_ * VQ_;   // 23040
constexpr float EPSf = 1e-5f;
constexpr int NSL = 16;          // score partial K-slices

// ---------------------------------------------------------------- K0: fold Wq into key side
__global__ __launch_bounds__(64)
void k0_precompute(const float* __restrict__ Wq, const float* __restrict__ bq,
                   const float* __restrict__ Wk, const float* __restrict__ bk,
                   short* __restrict__ MtA, float* __restrict__ bMp,
                   float* __restrict__ wb, float* __restrict__ cb) {
    int s  = blockIdx.x >> 6;
    int ci = blockIdx.x & 63;
    int cj = threadIdx.x;
    float m = 0.f;
    for (int c = 0; c < C_; ++c)
        m += Wq[(s * C_ + c) * C_ + ci] * Wk[(s * C_ + c) * C_ + cj];
    MtA[((cj >> 3) * 256 + s * C_ + ci) * 8 + (cj & 7)] = f2bs(m);
    if (cj == 0) {
        float v = 0.f;
        for (int c = 0; c < C_; ++c)
            v += Wq[(s * C_ + c) * C_ + ci] * bk[s * C_ + c];
        bMp[s * C_ + ci] = v;
    }
    if (ci == 0) {
        float v = 0.f;
        for (int c = 0; c < C_; ++c)
            v += bq[s * C_ + c] * Wk[(s * C_ + c) * C_ + cj];
        wb[s * C_ + cj] = v;
        if (cj == 0) {
            float v2 = 0.f;
            for (int c = 0; c < C_; ++c)
                v2 += bq[s * C_ + c] * bk[s * C_ + c];
            cb[s] = v2;
        }
    }
}

// ---------------------------------------------------------------- K0b: fold Wout into Wv
__global__ __launch_bounds__(256)
void k0b_wos(const float* __restrict__ Wout, const float* __restrict__ bout,
             const float* __restrict__ Wv, const float* __restrict__ bv,
             short* __restrict__ WosA, float* __restrict__ bos) {
    int cj = blockIdx.x;
    __shared__ float wvcol[C_];
    if (threadIdx.x < C_) wvcol[threadIdx.x] = Wv[threadIdx.x * C_ + cj];
    __syncthreads();
    int p = threadIdx.x;       // p = s*64 + o
    int s = p >> 6, o = p & 63;
    float acc = 0.f;
    for (int c = 0; c < C_; ++c)
        acc += Wout[o * (S_ * C_) + s * C_ + c] * wvcol[c];
    WosA[((cj >> 3) * 256 + p) * 8 + (cj & 7)] = f2bs(acc);
    if (cj == 0 && p < C_) {
        float a = bout[p];
        for (int k = 0; k < S_ * C_; ++k)
            a += Wout[p * (S_ * C_) + k] * bv[k & 63];
        bos[p] = a;
    }
}

// ---------------------------------------------------------------- K0c: xqT[n][g][t][u96][cc8] bf16
__global__ __launch_bounds__(256)
void k0c_xqt(const float* __restrict__ xq, short* __restrict__ xqT) {
    int tt = blockIdx.x;            // 64 tiles of 4 t
    int g  = blockIdx.y;
    int n  = blockIdx.z;
    int t0 = tt * 4;
    __shared__ float lds[8 * 360];  // [c][t*90+u], 11.5KB
    int tid = threadIdx.x;
    const float* src = xq + ((size_t)(n * 64 + g * 8) * 256 + t0) * 90;
#pragma unroll
    for (int i = tid; i < 720; i += 256) {
        int c = i / 90, r = i % 90;
        float4 v = *(const float4*)(src + (size_t)c * 23040 + r * 4);
        *(float4*)(&lds[c * 360 + r * 4]) = v;
    }
    __syncthreads();
    for (int e = tid; e < 4 * 96; e += 256) {
        int t = e / 96, u = e % 96;
        short8 pk;
#pragma unroll
        for (int j = 0; j < 8; ++j)
            pk[j] = (u < 90) ? f2bs(lds[j * 360 + t * 90 + u]) : (short)0;
        *(short8*)(xqT + (((size_t)(n * 8 + g) * 256 + t0 + t) * 96 + u) * 8) = pk;
    }
}

// ---------------------------------------------------------------- K1: MFMA kq = Mt @ x_k + bM -> kqT
// v3: direct dwordx2 epilogue (lane holds 4 consecutive ci), no LDS transpose.
__global__ __launch_bounds__(256)
void k1_mfma(const float* __restrict__ x_k, const short* __restrict__ MtA,
             const float* __restrict__ bMp, short* __restrict__ kqT) {
    int tb = blockIdx.x, n = blockIdx.y;
    int t0 = tb * 2;
    __shared__ __align__(16) short Ab[8 * 256 * 8]; // 32KB
    __shared__ __align__(16) short Bb[8 * 128 * 8]; // 16KB
    __shared__ float bmp_s[256];
    __shared__ float xs[3200];       // 12.8KB: [c32][100] = 32 ch x (2t x 50v)
    int tid = threadIdx.x;
    int wave = tid >> 6, lane = tid & 63, q = lane >> 5, c32 = lane & 31;
    if (tid < 256) bmp_s[tid] = bMp[tid];
    // A-stage via async global->LDS (MtA is L2-resident; 32 calls x 1KB)
    {
        const short8* Asrc = (const short8*)MtA;
#pragma unroll
        for (int it = 0; it < 8; ++it) {
            int call = wave * 8 + it;
            gload_lds16(Asrc + call * 64 + lane, (char*)Ab + call * 1024);
        }
    }
#pragma unroll
    for (int p = 0; p < 2; ++p) {
        for (int i4 = tid; i4 < 800; i4 += 256) {
            int cc = i4 / 25, o = i4 % 25;
            *(float4*)(&xs[cc * 100 + o * 4]) =
                *(const float4*)(x_k + ((size_t)(n * 64 + p * 32 + cc) * 256 + t0) * 50 + o * 4);
        }
        __syncthreads();
        for (int m = tid; m < 512; m += 256) {
            int kgl = m >> 7, c = m & 127, t = c >> 6, v = c & 63;
            short8 pk;
            if (v < VK_) {
#pragma unroll
                for (int j = 0; j < 8; ++j) pk[j] = f2bs(xs[(kgl * 8 + j) * 100 + t * 50 + v]);
            } else {
#pragma unroll
                for (int j = 0; j < 8; ++j) pk[j] = 0;
            }
            *(short8*)(Bb + ((p * 4 + kgl) * 128 + c) * 8) = pk;
        }
        __syncthreads();
    }
    asm volatile("s_waitcnt vmcnt(0)" ::: "memory");  // A-stage drained
    __builtin_amdgcn_s_barrier();
    f32x16 acc[2][4];
#pragma unroll
    for (int mt = 0; mt < 2; ++mt) {
#pragma unroll
        for (int r = 0; r < 16; ++r) {
            float b = bmp_s[wave * 64 + mt * 32 + (r & 3) + 8 * (r >> 2) + 4 * q];
#pragma unroll
            for (int nt = 0; nt < 4; ++nt) acc[mt][nt][r] = b;
        }
    }
#pragma unroll
    for (int ks = 0; ks < 4; ++ks) {
        int kg = 2 * ks + q;
        short8 a0 = *(const short8*)(Ab + (kg * 256 + wave * 64 + c32) * 8);
        short8 a1 = *(const short8*)(Ab + (kg * 256 + wave * 64 + 32 + c32) * 8);
#pragma unroll
        for (int nt = 0; nt < 4; ++nt) {
            short8 b = *(const short8*)(Bb + (kg * 128 + nt * 32 + c32) * 8);
            acc[0][nt] = __builtin_amdgcn_mfma_f32_32x32x16_bf16(a0, b, acc[0][nt], 0, 0, 0);
            acc[1][nt] = __builtin_amdgcn_mfma_f32_32x32x16_bf16(a1, b, acc[1][nt], 0, 0, 0);
        }
    }
    // direct stores: lane holds col (t,v); rows = 4-consecutive ci per rq group.
    int ns = n * 4 + wave;
#pragma unroll
    for (int mt = 0; mt < 2; ++mt)
#pragma unroll
        for (int nt = 0; nt < 4; ++nt) {
            int t = nt >> 1, v = (nt & 1) * 32 + c32;
            if (v < VK_) {
                f32x16 A = acc[mt][nt];
#pragma unroll
                for (int rq = 0; rq < 4; ++rq) {
                    short4v pk;
#pragma unroll
                    for (int rr = 0; rr < 4; ++rr) pk[rr] = f2bs(A[rq * 4 + rr]);
                    *(short4v*)(kqT + ((((size_t)(ns * 8 + mt * 4 + rq)) * 256 + t0 + t) * VK_ + v) * 8 + 4 * q) = pk;
                }
            }
        }
}

// ---------------------------------------------------------------- K3b: kbsum from x_k sliding sums
__global__ __launch_bounds__(128)
void k3b_kbsum(const float* __restrict__ x_k, const float* __restrict__ wb,
               const float* __restrict__ cb, float* __restrict__ kbsum) {
    int cjg = blockIdx.x;  // 32 groups of 2 cj
    int n = blockIdx.y;
    __shared__ float S[2][NL][VK_];
    for (int pr = threadIdx.x; pr < 2 * VK_; pr += 128) {
        int cjl = pr / VK_, v = pr % VK_;
        const float* base = x_k + ((size_t)(n * 64 + cjg * 2 + cjl) * 256) * VK_ + v;
        float a = 0.f;
        for (int t = 0; t < Tq_; ++t) a += base[t * VK_];
        S[cjl][0][v] = a;
        float run = a;
        for (int l = 1; l < NL; ++l) {
            run += base[(251 + l) * VK_] - base[(l - 1) * VK_];
            S[cjl][l][v] = run;
        }
    }
    __syncthreads();
    for (int e = threadIdx.x; e < S_ * NL * VK_; e += 128) {
        int s = e / (NL * VK_), r = e % (NL * VK_), l = r / VK_, v = r % VK_;
        float a = wb[s * 64 + cjg * 2] * S[0][l][v] + wb[s * 64 + cjg * 2 + 1] * S[1][l][v];
        if (cjg == 0) a += (float)Tq_ * cb[s];
        atomicAdd(&kbsum[((size_t)(n * 4 + s) * NL + l) * VK_ + v], a);
    }
}

// ---------------------------------------------------------------- K3: MFMA scores
// v5: 12-t chunks, depth-1 counted vmcnt, 62KB dbuf, XCD swizzle, setprio,
// dense partial layout [ns][l][gx][u][v].
__global__ __launch_bounds__(256)
void k3_mfma(const short* __restrict__ xqT, const short* __restrict__ kqT,
             float* __restrict__ partial) {
    int lin = blockIdx.x + 16 * blockIdx.y;   // 0..511
    int grp = lin & 7;                        // XCD
    int idx = lin >> 3;                       // 0..63
    int slice = grp + 8 * (idx >> 3);         // n*8+g, 8 slices per XCD
    int sub = idx & 7;                        // s*2+half
    int n = slice >> 3, g = slice & 7;
    int s = sub >> 1, half = sub & 1;
    int ns = n * 4 + s;
    int gx = g * 2 + half;                    // partial slice index 0..15
    __shared__ __align__(16) short sbuf[2][15872];   // 2 x 31744B = 62KB
    int tid = threadIdx.x;
    int wave = tid >> 6, lane = tid & 63;
    int q = lane >> 5, nl = lane & 31;
    int n1 = wave * 64 + nl, n2 = n1 + 32;
    int nc1 = min(n1, 249), nc2 = min(n2, 249);
    int l1 = nc1 / VK_, v1 = nc1 % VK_;
    int l2 = nc2 / VK_, v2 = nc2 % VK_;
    int bo1 = ((q + l1) * VK_ + v1) * 8;
    int bo2 = ((q + l2) * VK_ + v2) * 8;
    int ao = (q * 96 + nl) * 8;
    f32x16 acc[6];
#pragma unroll
    for (int i = 0; i < 6; ++i)
#pragma unroll
        for (int r = 0; r < 16; ++r) acc[i][r] = 0.f;
    const short* asrc = xqT + (size_t)(n * 8 + g) * 256 * 768;
    const short* bsrc = kqT + (size_t)(ns * 8 + g) * 256 * 400;
    int c0 = half * 10, nch = half ? 11 : 10;
    int ncall = (wave == 3) ? 7 : 8;

    auto stage = [&](int buf, int ch) {
        int t0 = ch * 12;
        const short8* aS = (const short8*)(asrc + t0 * 768);
        const short8* bS = (const short8*)(bsrc + t0 * 400);
        char* db = (char*)(&sbuf[buf][0]);
        for (int it = 0; it < ncall; ++it) {
            int call = wave * 8 + it;            // 0..30 (call 31 never issued)
            int i = call * 64 + lane;            // linear lane-load index
            const void* gsrc = (i < 1152) ? (const void*)(aS + i)
                                          : (const void*)(bS + min(i - 1152, 799));
            gload_lds16(gsrc, db + call * 1024); // dst wave-uniform; HW adds lane*16
        }
    };

    stage(0, c0);
    for (int ci = 0; ci < nch; ++ci) {
        int cur = ci & 1;
        if (ci + 1 < nch) {
            stage(cur ^ 1, c0 + ci + 1);
            if (wave == 3) asm volatile("s_waitcnt vmcnt(7)" ::: "memory");
            else           asm volatile("s_waitcnt vmcnt(8)" ::: "memory");
        } else {
            asm volatile("s_waitcnt vmcnt(0)" ::: "memory");
        }
        __builtin_amdgcn_s_barrier();
        const short* xa  = &sbuf[cur][0];
        const short* kbs = &sbuf[cur][9216];     // B starts at byte 18432
        __builtin_amdgcn_s_setprio(1);
#pragma unroll
        for (int ts = 0; ts < 6; ++ts) {
            short8 a0 = *(const short8*)(xa + ao + ts * 1536);
            short8 a1 = *(const short8*)(xa + ao + 256 + ts * 1536);
            short8 a2 = *(const short8*)(xa + ao + 512 + ts * 1536);
            short8 b0 = *(const short8*)(kbs + bo1 + ts * 800);
            short8 b1 = *(const short8*)(kbs + bo2 + ts * 800);
            acc[0] = __builtin_amdgcn_mfma_f32_32x32x16_bf16(a0, b0, acc[0], 0, 0, 0);
            acc[1] = __builtin_amdgcn_mfma_f32_32x32x16_bf16(a1, b0, acc[1], 0, 0, 0);
            acc[2] = __builtin_amdgcn_mfma_f32_32x32x16_bf16(a2, b0, acc[2], 0, 0, 0);
            acc[3] = __builtin_amdgcn_mfma_f32_32x32x16_bf16(a0, b1, acc[3], 0, 0, 0);
            acc[4] = __builtin_amdgcn_mfma_f32_32x32x16_bf16(a1, b1, acc[4], 0, 0, 0);
            acc[5] = __builtin_amdgcn_mfma_f32_32x32x16_bf16(a2, b1, acc[5], 0, 0, 0);
        }
        __builtin_amdgcn_s_setprio(0);
        __builtin_amdgcn_s_barrier();            // protect buf[cur] before re-stage
    }
    // dense epilogue: partial[((ns*5+l)*16+gx)][u][v]
#pragma unroll
    for (int inb = 0; inb < 2; ++inb) {
        int ng = wave * 64 + inb * 32 + nl;
        if (ng < 250) {
            int l = ng / VK_, v = ng % VK_;
            float* pb = partial + (((size_t)(ns * 5 + l) * NSL + gx) * 90) * VK_ + v;
#pragma unroll
            for (int iu = 0; iu < 3; ++iu) {
#pragma unroll
                for (int r = 0; r < 16; ++r) {
                    int u2 = iu * 32 + (r & 3) + 8 * (r >> 2) + 4 * q;
                    if (u2 < 90) pb[(size_t)u2 * VK_] = acc[inb * 3 + iu][r];
                }
            }
        }
    }
}

// ---------------------------------------------------------------- K4: reduce slices + combine lags + softmax
// v3: writes att directly in k6's packed layout att_pk[n][kg32][u96][cc8]
// (k = s*64+v; pad slots pre-zeroed by memset).
__global__ __launch_bounds__(256)
void k4_softmax(const float* __restrict__ partial, const float* __restrict__ kbsum,
                short* __restrict__ att_pk) {
    int ug = blockIdx.x;
    int ns = blockIdx.y;
    int u0 = ug * 15;
    __shared__ float sred[NL * 15 * VK_];
    for (int idx = threadIdx.x; idx < NL * 15 * VK_; idx += 256) {
        int l = idx / (15 * VK_), r = idx % (15 * VK_);
        int u2 = r / VK_, v = r % VK_;
        const float* p = partial + ((size_t)(ns * NL + l) * NSL) * 90 * VK_
                         + (u0 + u2) * VK_ + v;
        float a = 0.f;
#pragma unroll
        for (int sl = 0; sl < NSL; ++sl) a += p[(size_t)sl * 90 * VK_];
        sred[idx] = a;
    }
    __syncthreads();
    if (threadIdx.x < 15) {
        int u2 = threadIdx.x;
        const float inv_scale = rsqrtf((float)(C_ * Tq_));
        float pv[VK_];
        float pmax = -1e30f;
#pragma unroll
        for (int v = 0; v < VK_; ++v) {
            float mx = -1e30f, mn = 0.f;
#pragma unroll
            for (int l = 0; l < NL; ++l) {
                float sl = (sred[(l * 15 + u2) * VK_ + v] + kbsum[((size_t)ns * NL + l) * VK_ + v]) * inv_scale;
                mx = fmaxf(mx, sl); mn += sl;
            }
            pv[v] = 0.5f * (mx + mn * (1.f / NL));
            pmax = fmaxf(pmax, pv[v]);
        }
        float sum = 0.f;
#pragma unroll
        for (int v = 0; v < VK_; ++v) { pv[v] = __expf(pv[v] - pmax); sum += pv[v]; }
        float inv = 1.f / sum;
        int n = ns >> 2, s = ns & 3;
        short* base = att_pk + ((size_t)(n * 32 + s * 8)) * 96 * 8;
#pragma unroll
        for (int v = 0; v < VK_; ++v)
            base[(size_t)((v >> 3) * 96 + (u0 + u2)) * 8 + (v & 7)] = f2bs(pv[v] * inv);
    }
}

// ---------------------------------------------------------------- K5: MFMA wv_pack
// v3: flipped operands; direct unconditional 8B stores.
__global__ __launch_bounds__(256)
void k5_mfma(const float* __restrict__ x_v, const short* __restrict__ WosA,
             short* __restrict__ wv_pack) {
    int tb = blockIdx.x, n = blockIdx.y;
    int t0 = tb * 2;
    __shared__ __align__(16) short Ab[8 * 256 * 8]; // 32KB (Wos, B operand)
    __shared__ __align__(16) short Bb[8 * 128 * 8]; // 16KB (x_v, A operand)
    __shared__ float xs[3200];       // 12.8KB
    int tid = threadIdx.x;
    int wave = tid >> 6, lane = tid & 63, q = lane >> 5, c32 = lane & 31;
    {
        const short8* Asrc = (const short8*)WosA;
#pragma unroll
        for (int it = 0; it < 8; ++it) {
            int call = wave * 8 + it;
            gload_lds16(Asrc + call * 64 + lane, (char*)Ab + call * 1024);
        }
    }
#pragma unroll
    for (int p = 0; p < 2; ++p) {
        for (int i4 = tid; i4 < 800; i4 += 256) {
            int cc = i4 / 25, o = i4 % 25;
            *(float4*)(&xs[cc * 100 + o * 4]) =
                *(const float4*)(x_v + ((size_t)(n * 64 + p * 32 + cc) * 256 + t0) * 50 + o * 4);
        }
        __syncthreads();
        for (int m = tid; m < 512; m += 256) {
            int kgl = m >> 7, c = m & 127, t = c >> 6, v = c & 63;
            short8 pk;
            if (v < VK_) {
#pragma unroll
                for (int j = 0; j < 8; ++j) pk[j] = f2bs(xs[(kgl * 8 + j) * 100 + t * 50 + v]);
            } else {
#pragma unroll
                for (int j = 0; j < 8; ++j) pk[j] = 0;
            }
            *(short8*)(Bb + ((p * 4 + kgl) * 128 + c) * 8) = pk;
        }
        __syncthreads();
    }
    asm volatile("s_waitcnt vmcnt(0)" ::: "memory");
    __builtin_amdgcn_s_barrier();
    f32x16 acc[4][2];
#pragma unroll
    for (int m = 0; m < 4; ++m)
#pragma unroll
        for (int nn2 = 0; nn2 < 2; ++nn2)
#pragma unroll
            for (int r = 0; r < 16; ++r) acc[m][nn2][r] = 0.f;
#pragma unroll
    for (int ks = 0; ks < 4; ++ks) {
        int kg = 2 * ks + q;
        short8 bw0 = *(const short8*)(Ab + (kg * 256 + wave * 64 + c32) * 8);
        short8 bw1 = *(const short8*)(Ab + (kg * 256 + wave * 64 + 32 + c32) * 8);
#pragma unroll
        for (int m = 0; m < 4; ++m) {
            short8 ax = *(const short8*)(Bb + (kg * 128 + m * 32 + c32) * 8);
            acc[m][0] = __builtin_amdgcn_mfma_f32_32x32x16_bf16(ax, bw0, acc[m][0], 0, 0, 0);
            acc[m][1] = __builtin_amdgcn_mfma_f32_32x32x16_bf16(ax, bw1, acc[m][1], 0, 0, 0);
        }
    }
#pragma unroll
    for (int m = 0; m < 4; ++m)
#pragma unroll
        for (int nn2 = 0; nn2 < 2; ++nn2) {
            int o = nn2 * 32 + c32;
            int t = t0 + (m >> 1);
            f32x16 A = acc[m][nn2];
            size_t base = (((size_t)(n * 256 + t) * 32) + wave * 8 + (m & 1) * 4) * 512 + o * 8 + 4 * q;
#pragma unroll
            for (int rq = 0; rq < 4; ++rq) {
                short4v pk;
#pragma unroll
                for (int rr = 0; rr < 4; ++rr) pk[rr] = f2bs(A[rq * 4 + rr]);
                *(short4v*)(wv_pack + base + (size_t)rq * 512) = pk;
            }
        }
}

// ---------------------------------------------------------------- K6: MFMA y-path, K=256
// v2: async gload_lds16 staging of pre-packed att_pk (48 x 1KB), LDS-transpose
// epilogue with contiguous 16B row stores (no scalar 2B RMW writes).
__global__ __launch_bounds__(256)
void k6_mfma(const short* __restrict__ att_pk, const short* __restrict__ wv_pack,
             const float* __restrict__ bos, bf16* __restrict__ out_pre) {
    int tc = blockIdx.x, n = blockIdx.y;
    __shared__ __align__(16) short att_p[32 * 96 * 8]; // 48KB [kg][u][cc8]; reused for transpose
    __shared__ float bos_s[64];
    int tid = threadIdx.x;
    int wave = tid >> 6, lane = tid & 63;
    int q = lane >> 5, c = lane & 31;
    if (tid < 64) bos_s[tid] = bos[tid];
    {
        const short8* src = (const short8*)(att_pk + (size_t)n * 24576);
#pragma unroll
        for (int it = 0; it < 12; ++it) {
            int call = wave * 12 + it;           // 0..47, 1KB each
            gload_lds16(src + call * 64 + lane, (char*)att_p + call * 1024);
        }
    }
    asm volatile("s_waitcnt vmcnt(0)" ::: "memory");
    __syncthreads();
    int t = tc * 4 + wave;
    f32x16 acc[6];
#pragma unroll
    for (int ot = 0; ot < 2; ++ot)
#pragma unroll
        for (int r = 0; r < 16; ++r) {
            float b = bos_s[ot * 32 + (r & 3) + 8 * (r >> 2) + 4 * q];
            acc[ot * 3 + 0][r] = b; acc[ot * 3 + 1][r] = b; acc[ot * 3 + 2][r] = b;
        }
    const short* wbase = wv_pack + (size_t)(n * 256 + t) * (32 * 512);
#pragma unroll
    for (int st = 0; st < 16; ++st) {
        int gq = 2 * st + q;
        short8 a0 = *(const short8*)(wbase + (gq * 64 + c) * 8);
        short8 a1 = *(const short8*)(wbase + (gq * 64 + 32 + c) * 8);
        short8 b0 = *(const short8*)(att_p + (gq * 96 + c) * 8);
        short8 b1 = *(const short8*)(att_p + (gq * 96 + 32 + c) * 8);
        short8 b2 = *(const short8*)(att_p + (gq * 96 + 64 + c) * 8);
        acc[0] = __builtin_amdgcn_mfma_f32_32x32x16_bf16(a0, b0, acc[0], 0, 0, 0);
        acc[1] = __builtin_amdgcn_mfma_f32_32x32x16_bf16(a0, b1, acc[1], 0, 0, 0);
        acc[2] = __builtin_amdgcn_mfma_f32_32x32x16_bf16(a0, b2, acc[2], 0, 0, 0);
        acc[3] = __builtin_amdgcn_mfma_f32_32x32x16_bf16(a1, b0, acc[3], 0, 0, 0);
        acc[4] = __builtin_amdgcn_mfma_f32_32x32x16_bf16(a1, b1, acc[4], 0, 0, 0);
        acc[5] = __builtin_amdgcn_mfma_f32_32x32x16_bf16(a1, b2, acc[5], 0, 0, 0);
    }
    // transpose through LDS (att_p dead): per-wave region [64 o][96 u] shorts
    __syncthreads();
    short* tw = att_p + wave * 6144;
#pragma unroll
    for (int ot = 0; ot < 2; ++ot)
#pragma unroll
        for (int ut = 0; ut < 3; ++ut) {
            int u2 = ut * 32 + c;
            f32x16 A = acc[ot * 3 + ut];
#pragma unroll
            for (int r = 0; r < 16; ++r) {
                int o = ot * 32 + (r & 3) + 8 * (r >> 2) + 4 * q;
                tw[o * 96 + u2] = f2bs(A[r]);
            }
        }
    __syncthreads();
    // store rows: per wave 64 o x 12 u8-chunks (u8<11 full 16B, u8==11 -> 4B)
    bf16* obase = out_pre + ((size_t)(n * 64) * 256 + t) * 90;
#pragma unroll
    for (int i = 0; i < 12; ++i) {
        int unit = i * 64 + lane;     // 0..767
        int o = unit / 12, u8 = unit % 12;
        bf16* dst = obase + (size_t)o * 256 * 90 + u8 * 8;
        const short* srcl = tw + o * 96 + u8 * 8;
        if (u8 < 11) *(short8*)dst = *(const short8*)srcl;
        else         *(int*)dst = *(const int*)srcl;   // u = 88,89
    }
}

// ---------------------------------------------------------------- K7: MFMA down conv
__global__ __launch_bounds__(256)
void k7_mfma(const float* __restrict__ X, const float* __restrict__ W,
             const float* __restrict__ bias, bf16* __restrict__ out) {
    int cb = blockIdx.x, n = blockIdx.y;
    int col0 = cb * 256;
    __shared__ __align__(16) short A[8 * 64 * 8];  // 8KB
    __shared__ __align__(16) short B[8 * 256 * 8]; // 32KB
    __shared__ float bias_s[64];
    __shared__ float xs[2048];                     // 8KB: [cl][256]
    int tid = threadIdx.x;
    if (tid < 64) bias_s[tid] = bias[tid];
    for (int idx = tid; idx < 4096; idx += 256) {
        int o = idx >> 6, k = idx & 63;
        A[((k >> 3) * 64 + o) * 8 + (k & 7)] = f2bs(W[o * 64 + k]);
    }
#pragma unroll
    for (int p = 0; p < 8; ++p) {
        for (int i4 = tid; i4 < 512; i4 += 256) {
            int cl = i4 >> 6, o = i4 & 63;
            *(float4*)(&xs[cl * 256 + o * 4]) =
                *(const float4*)(X + (size_t)(n * 64 + p * 8 + cl) * COLS + col0 + o * 4);
        }
        __syncthreads();
        {
            short8 pk;
#pragma unroll
            for (int j = 0; j < 8; ++j) pk[j] = f2bs(xs[j * 256 + tid]);
            *(short8*)(B + (p * 256 + tid) * 8) = pk;
        }
        __syncthreads();
    }
    int wave = tid >> 6, lane = tid & 63, q = lane >> 5, c32 = lane & 31;
    f32x16 acc[2][2];
#pragma unroll
    for (int mt = 0; mt < 2; ++mt)
#pragma unroll
        for (int r = 0; r < 16; ++r) {
            float b = bias_s[mt * 32 + (r & 3) + 8 * (r >> 2) + 4 * q];
            acc[mt][0][r] = b; acc[mt][1][r] = b;
        }
#pragma unroll
    for (int ks = 0; ks < 4; ++ks) {
        int kg = 2 * ks + q;
        short8 a0 = *(const short8*)(A + (kg * 64 + c32) * 8);
        short8 a1 = *(const short8*)(A + (kg * 64 + 32 + c32) * 8);
#pragma unroll
        for (int i = 0; i < 2; ++i) {
            short8 b = *(const short8*)(B + (kg * 256 + (wave * 2 + i) * 32 + c32) * 8);
            acc[0][i] = __builtin_amdgcn_mfma_f32_32x32x16_bf16(a0, b, acc[0][i], 0, 0, 0);
            acc[1][i] = __builtin_amdgcn_mfma_f32_32x32x16_bf16(a1, b, acc[1][i], 0, 0, 0);
        }
    }
#pragma unroll
    for (int mt = 0; mt < 2; ++mt)
#pragma unroll
        for (int i = 0; i < 2; ++i) {
            int col = col0 + (wave * 2 + i) * 32 + c32;
#pragma unroll
            for (int r = 0; r < 16; ++r) {
                int o = mt * 32 + (r & 3) + 8 * (r >> 2) + 4 * q;
                out[(size_t)(n * 64 + o) * COLS + col] = f2b(acc[mt][i][r]);
            }
        }
}

// ---------------------------------------------------------------- K8: per-channel sum/sumsq (vectorized short8)
__global__ __launch_bounds__(256)
void k8_stats(const bf16* __restrict__ out_pre, const bf16* __restrict__ d_pre,
              float* __restrict__ stats) {
    int path = blockIdx.x >> 9;
    int b = blockIdx.x & 511;
    int o = b >> 3, n = b & 7;
    const bf16* p = (path ? d_pre : out_pre) + ((size_t)n * C_ + o) * COLS;
    float s = 0.f, sq = 0.f;
    for (int i8 = threadIdx.x; i8 < COLS / 8; i8 += 256) {
        short8 v8 = *(const short8*)(p + i8 * 8);
#pragma unroll
        for (int j = 0; j < 8; ++j) {
            float x = s2f(v8[j]);
            s += x; sq += x * x;
        }
    }
#pragma unroll
    for (int off = 32; off > 0; off >>= 1) {
        s  += __shfl_down(s, off, 64);
        sq += __shfl_down(sq, off, 64);
    }
    __shared__ float red[8];
    int wid = threadIdx.x >> 6, lane = threadIdx.x & 63;
    if (lane == 0) { red[wid * 2] = s; red[wid * 2 + 1] = sq; }
    __syncthreads();
    if (threadIdx.x == 0) {
        float S = 0.f, Q = 0.f;
        for (int w2 = 0; w2 < 4; ++w2) { S += red[w2 * 2]; Q += red[w2 * 2 + 1]; }
        atomicAdd(&stats[path * 128 + o * 2], S);
        atomicAdd(&stats[path * 128 + o * 2 + 1], Q);
    }
}

// ---------------------------------------------------------------- K9: BN + BN + add + leaky relu (vectorized)
__global__ __launch_bounds__(256)
void k9_final(const bf16* __restrict__ out_pre, const bf16* __restrict__ d_pre,
              const float* __restrict__ stats,
              const float* __restrict__ gamma_out, const float* __restrict__ beta_out,
              const float* __restrict__ gamma_down, const float* __restrict__ beta_down,
              float* __restrict__ out) {
    const float invM = 1.f / ((float)N_ * COLS);
    size_t total8 = (size_t)N_ * C_ * COLS / 8;   // 1474560
    size_t stride = (size_t)gridDim.x * blockDim.x;
    for (size_t i8 = (size_t)blockIdx.x * blockDim.x + threadIdx.x; i8 < total8; i8 += stride) {
        size_t idx = i8 * 8;
        int o = (int)((idx / COLS) % C_);         // COLS % 8 == 0 -> o uniform over pack
        float my = stats[o * 2] * invM;
        float vy = stats[o * 2 + 1] * invM - my * my;
        float md = stats[128 + o * 2] * invM;
        float vd = stats[128 + o * 2 + 1] * invM - md * md;
        float ay = rsqrtf(vy + EPSf) * gamma_out[o];
        float by = beta_out[o] - my * ay;
        float ad = rsqrtf(vd + EPSf) * gamma_down[o];
        float bd = beta_down[o] - md * ad;
        short8 y8 = *(const short8*)(out_pre + idx);
        short8 d8 = *(const short8*)(d_pre + idx);
        float rr[8];
#pragma unroll
        for (int j = 0; j < 8; ++j) {
            float r = (s2f(y8[j]) * ay + by) + (s2f(d8[j]) * ad + bd);
            rr[j] = r > 0.f ? r : 0.1f * r;
        }
        *(float4*)(out + idx)     = make_float4(rr[0], rr[1], rr[2], rr[3]);
        *(float4*)(out + idx + 4) = make_float4(rr[4], rr[5], rr[6], rr[7]);
    }
}

// ----------------------------------------------------------------
extern "C" void kernel_launch(void* const* d_in, const int* in_sizes, int n_in,
                              void* d_out, int out_size, void* d_ws, size_t ws_size,
                              hipStream_t stream) {
    (void)in_sizes; (void)n_in; (void)out_size; (void)ws_size;
    const float* x_q  = (const float*)d_in[0];
    const float* x_k  = (const float*)d_in[1];
    const float* x_v  = (const float*)d_in[2];
    const float* Wq   = (const float*)d_in[3];
    const float* bq   = (const float*)d_in[4];
    const float* Wk   = (const float*)d_in[5];
    const float* bk   = (const float*)d_in[6];
    const float* Wv   = (const float*)d_in[7];
    const float* bv   = (const float*)d_in[8];
    const float* Wout = (const float*)d_in[9];
    const float* bout = (const float*)d_in[10];
    const float* gamma_out  = (const float*)d_in[11];
    const float* beta_out   = (const float*)d_in[12];
    const float* Wdown = (const float*)d_in[13];
    const float* bdown = (const float*)d_in[14];
    const float* gamma_down = (const float*)d_in[15];
    const float* beta_down  = (const float*)d_in[16];

    char* w = (char*)d_ws;
    size_t off = 0;
    auto nxt = [&](size_t bytes) {
        char* p = w + off;
        off += (bytes + 255) & ~(size_t)255;
        return p;
    };
    // small persistent buffers
    short* MtA   = (short*)nxt((size_t)8 * 256 * 8 * 2);   // 32KB
    float* bMp   = (float*)nxt(256 * 4);
    float* wbp   = (float*)nxt((size_t)S_ * C_ * 4);
    float* cbp   = (float*)nxt((size_t)S_ * 4);
    short* WosA  = (short*)nxt((size_t)8 * 256 * 8 * 2);   // 32KB
    float* bos   = (float*)nxt((size_t)C_ * 4);
    float* kbsum = (float*)nxt((size_t)N_ * S_ * NL * VK_ * 4); // 32KB
    short* att_pk = (short*)nxt((size_t)N_ * 32 * 96 * 8 * 2);  // 393KB packed att
    float* stats = (float*)nxt(256 * 4);
    // regionA: xqT (k0c->k3) then out_pre (k6->k8,k9)
    char* regionA = nxt((size_t)N_ * 8 * T_ * 96 * 8 * 2);            // 25.2MB
    short* xqT    = (short*)regionA;
    bf16*  out_pre = (bf16*)regionA;
    // regionB: kqT (k1->k3) then d_pre (k7->k8,k9)
    char* regionB = nxt((size_t)N_ * S_ * 8 * T_ * VK_ * 8 * 2);      // 52.4MB
    short* kqT   = (short*)regionB;
    bf16*  d_pre = (bf16*)regionB;
    // regionC: partial (k3->k4) then wv_pack (k5->k6)
    char* regionC = nxt((size_t)N_ * T_ * 32 * 512 * 2);              // 67.1MB
    float* partial = (float*)regionC;
    short* wv_pack = (short*)regionC;

    hipMemsetAsync(stats, 0, 256 * 4, stream);
    hipMemsetAsync(kbsum, 0, (size_t)N_ * S_ * NL * VK_ * 4, stream);
    hipMemsetAsync(att_pk, 0, (size_t)N_ * 32 * 96 * 8 * 2, stream);

    k0_precompute<<<S_ * C_, 64, 0, stream>>>(Wq, bq, Wk, bk, MtA, bMp, wbp, cbp);
    k0b_wos<<<C_, 256, 0, stream>>>(Wout, bout, Wv, bv, WosA, bos);
    k0c_xqt<<<dim3(64, 8, N_), 256, 0, stream>>>(x_q, xqT);
    k1_mfma<<<dim3(128, N_), 256, 0, stream>>>(x_k, MtA, bMp, kqT);
    k3b_kbsum<<<dim3(32, N_), 128, 0, stream>>>(x_k, wbp, cbp, kbsum);
    k3_mfma<<<dim3(NSL, N_ * S_), 256, 0, stream>>>(xqT, kqT, partial);
    k4_softmax<<<dim3(6, N_ * S_), 256, 0, stream>>>(partial, kbsum, att_pk);
    k5_mfma<<<dim3(128, N_), 256, 0, stream>>>(x_v, WosA, wv_pack);
    k6_mfma<<<dim3(T_ / 4, N_), 256, 0, stream>>>(att_pk, wv_pack, bos, out_pre);
    k7_mfma<<<dim3(COLS / 256, N_), 256, 0, stream>>>(x_q, Wdown, bdown, d_pre);
    k8_stats<<<1024, 256, 0, stream>>>(out_pre, d_pre, stats);
    k9_final<<<2880, 256, 0, stream>>>(out_pre, d_pre, stats, gamma_out, beta_out,
                                       gamma_down, beta_down, (float*)d_out);
}